// Round 8
// baseline (491.849 us; speedup 1.0000x reference)
//
#include <hip/hip_runtime.h>
#include <hip/hip_fp16.h>
#include <math.h>

constexpr float NEG_SLOPE = 0.2f;
constexpr float EPS_BN = 1e-5f;
constexpr float EPS_SM = 1e-16f;

typedef _Float16 half8 __attribute__((ext_vector_type(8)));
typedef float f32x4 __attribute__((ext_vector_type(4)));

__device__ __forceinline__ float lrelu(float x){ return x >= 0.f ? x : NEG_SLOPE * x; }

typedef const __attribute__((address_space(1))) unsigned int* gas_u32;
typedef __attribute__((address_space(3))) unsigned int* las_u32;

__device__ __forceinline__ void llds16(const _Float16* g, _Float16* l){
  __builtin_amdgcn_global_load_lds((gas_u32)(const void*)g, (las_u32)(void*)l, 16, 0, 0);
}

// ---------------- prep1: x->fp16, W0 transpose, post-GEMM B for layers 1/2,
// Va = W_h . a_h attention projections, cnt histogram (FIRE-AND-FORGET atomic:
// result unused -> no return, no wave stall), cnt2/bn/tick zeroing ----------------
__global__ void k_prep1(const float* __restrict__ x, _Float16* __restrict__ xh, int n8,
                        const int* __restrict__ ei, int E, int* __restrict__ cnt,
                        int* __restrict__ cnt2, int Nn,
                        const float* __restrict__ W0, const float* __restrict__ W1,
                        const float* __restrict__ W2, _Float16* __restrict__ Wt0,
                        _Float16* __restrict__ Wtp1, _Float16* __restrict__ Wtp2,
                        const float* __restrict__ as1, const float* __restrict__ ad1,
                        const float* __restrict__ as2, const float* __restrict__ ad2,
                        float* __restrict__ va,
                        float* __restrict__ bn, int* __restrict__ tick){
  int t = blockIdx.x * blockDim.x + threadIdx.x;
  if (t < n8){
    const float4* p = (const float4*)(x + (size_t)t * 8);
    float4 v0 = p[0], v1 = p[1];
    half8 h = {(_Float16)v0.x, (_Float16)v0.y, (_Float16)v0.z, (_Float16)v0.w,
               (_Float16)v1.x, (_Float16)v1.y, (_Float16)v1.z, (_Float16)v1.w};
    *(half8*)(xh + (size_t)t * 8) = h;
  }
  if (t < E) atomicAdd(&cnt[ei[E + t]], 1);   // histogram only; rank computed in fill
  if (t < Nn) cnt2[t] = 0;                    // fresh counters for on-the-fly rank
  if (t < 256) bn[t] = 0.f;
  if (t < 4) tick[t] = 0;
  if (t < 65536){
    int c = t & 255, k = t >> 8;
    Wt0[(size_t)c * 256 + k] = (_Float16)W0[(size_t)k * 256 + c];
  } else if (t < 81920){
    // post-GEMM B for layer 1: Wtp1[c][r=h*64+k] = 0.25*W1[k][h*64+c], c<64
    int u = t - 65536; int c = u & 63, r = u >> 6;
    Wtp1[(size_t)c * 256 + r] = (_Float16)(0.25f * W1[(size_t)(r & 63) * 256 + (r >> 6) * 64 + c]);
  } else if (t < 98304){
    int u = t - 81920; int c = u & 63, r = u >> 6;
    Wtp2[(size_t)c * 256 + r] = (_Float16)(0.25f * W2[(size_t)(r & 63) * 256 + (r >> 6) * 64 + c]);
  } else if (t < 99328){
    // Va[layer][j][sd*4+h] = sum_k W[j][h*64+k] * a[h][k]
    int u = t - 98304;
    int layer = u >> 9;
    int sd = (u >> 8) & 1;
    int u2 = u & 255;
    int c = u2 >> 2, h = u2 & 3;
    const float* Wl = layer ? W2 : W1;
    const float* av = layer ? (sd ? ad2 : as2) : (sd ? ad1 : as1);
    float acc = 0.f;
    #pragma unroll 4
    for (int k = 0; k < 64; k++)
      acc += Wl[(size_t)c * 256 + h * 64 + k] * av[h * 64 + k];
    va[layer * 512 + c * 8 + sd * 4 + h] = acc;
  }
}

// ---------------- CSR scans (degree = cnt[i] + 1 for the self-loop) ----------------
__global__ __launch_bounds__(256) void k_bsumscan(const int* __restrict__ cnt, int n, int chunk,
                                                  int* __restrict__ part, int* __restrict__ ptr,
                                                  int* __restrict__ tick){
  __shared__ int s[256];
  __shared__ int amLast;
  int b = blockIdx.x, t = threadIdx.x;
  int lo = b * chunk, hi = min(n, lo + chunk);
  int v = 0;
  for (int i = lo + t; i < hi; i += 256) v += cnt[i] + 1;
  s[t] = v;
  __syncthreads();
  #pragma unroll
  for (int off = 128; off > 0; off >>= 1){
    if (t < off) s[t] += s[t + off];
    __syncthreads();
  }
  if (t == 0) part[b] = s[0];
  __threadfence();
  if (t == 0) amLast = (atomicAdd(tick, 1) == (int)gridDim.x - 1) ? 1 : 0;
  __syncthreads();
  if (amLast){
    int pv = atomicAdd(&part[t], 0);
    s[t] = pv;
    __syncthreads();
    #pragma unroll
    for (int off = 1; off < 256; off <<= 1){
      int u = (t >= off) ? s[t - off] : 0;
      __syncthreads();
      s[t] += u;
      __syncthreads();
    }
    part[t] = s[t] - pv;
    if (t == 255) ptr[n] = s[255];
  }
}

__global__ __launch_bounds__(256) void k_localscan(const int* __restrict__ cnt, const int* __restrict__ part,
                                                   int n, int chunk, int* __restrict__ ptr,
                                                   int* __restrict__ csr_src){
  __shared__ int s[256];
  int b = blockIdx.x, t = threadIdx.x;
  int i = b * chunk + t;
  int c = (t < chunk && i < n) ? cnt[i] : 0;
  int v = (t < chunk && i < n) ? c + 1 : 0;
  s[t] = v;
  __syncthreads();
  #pragma unroll
  for (int off = 1; off < 256; off <<= 1){
    int u = (t >= off) ? s[t - off] : 0;
    __syncthreads();
    s[t] += u;
    __syncthreads();
  }
  if (t < chunk && i < n){
    int ex = part[b] + s[t] - v;
    ptr[i] = ex;
    csr_src[ex + c] = i;     // self-loop after the c ranked edges
  }
}

// ---------------- layer-0 MFMA GEMM: 128 rows x 256 cols; fused csr fill.
// Fill computes rank ON THE FLY (atomicAdd w/ return) — hidden under the
// concurrent MFMA blocks; XCD binning shards each dst's counter to one bin. ----------------
template<int LAYER>
__global__ __launch_bounds__(256, 2) void k_gemm(const _Float16* __restrict__ Xh,
    const _Float16* __restrict__ Wt, const float* __restrict__ a_s, const float* __restrict__ a_d,
    __half* __restrict__ hb, float* __restrict__ al, float* __restrict__ ar, int nrows,
    const int* __restrict__ ei, int E, int* __restrict__ cnt2,
    const int* __restrict__ rowptr, int* __restrict__ csr_src,
    int gemmBlocks, int N){
  constexpr int K = 256;
  if (LAYER == 0 && (int)blockIdx.x >= gemmBlocks){
    int fb = (int)blockIdx.x - gemmBlocks;
    int xcd = (int)blockIdx.x & 7;          // heuristic block->XCD
    int grp = fb >> 3;
    int ngrp = ((int)gridDim.x - gemmBlocks) >> 3;
    int nPer = N >> 3;
    int lo = xcd * nPer;
    int hi = (xcd == 7) ? N : lo + nPer;
    int stride = ngrp * 256;
    for (int e = grp * 256 + (int)threadIdx.x; e < E; e += stride){
      int dst = ei[E + e];
      if (dst >= lo && dst < hi)
        csr_src[rowptr[dst] + atomicAdd(&cnt2[dst], 1)] = ei[e];
    }
    return;
  }
  __shared__ _Float16 Alds[4][129][8];
  __shared__ _Float16 Blds[4][257][8];
  int tid = threadIdx.x;
  int m0 = blockIdx.x * 128;
  int w = tid >> 6, l = tid & 63;
  int lm = l & 15, lq = l >> 4;
  f32x4 acc[8][4] = {};

  for (int k0 = 0; k0 < K; k0 += 32){
    #pragma unroll
    for (int it = 0; it < 2; it++){
      int gr = m0 + it * 64 + l;
      if (gr < nrows)
        llds16(Xh + (size_t)gr * K + k0 + w * 8, &Alds[w][it * 64][0]);
    }
    #pragma unroll
    for (int it = 0; it < 4; it++){
      int col = it * 64 + l;
      llds16(Wt + (size_t)col * K + k0 + w * 8, &Blds[w][it * 64][0]);
    }
    __syncthreads();
    half8 af[8];
    #pragma unroll
    for (int mf = 0; mf < 8; mf++) af[mf] = *(const half8*)&Alds[lq][mf * 16 + lm][0];
    #pragma unroll
    for (int j = 0; j < 4; j++){
      half8 bf = *(const half8*)&Blds[lq][(w * 4 + j) * 16 + lm][0];
      #pragma unroll
      for (int mf = 0; mf < 8; mf++)
        acc[mf][j] = __builtin_amdgcn_mfma_f32_16x16x32_f16(af[mf], bf, acc[mf][j], 0, 0, 0);
    }
    __syncthreads();
  }

  float asv[4], adv[4];
  #pragma unroll
  for (int j = 0; j < 4; j++){
    asv[j] = a_s[w * 64 + j * 16 + lm];
    adv[j] = a_d[w * 64 + j * 16 + lm];
  }
  #pragma unroll
  for (int mf = 0; mf < 8; mf++){
    #pragma unroll
    for (int reg = 0; reg < 4; reg++){
      float sl = acc[mf][0][reg] * asv[0] + acc[mf][1][reg] * asv[1]
               + acc[mf][2][reg] * asv[2] + acc[mf][3][reg] * asv[3];
      float sr = acc[mf][0][reg] * adv[0] + acc[mf][1][reg] * adv[1]
               + acc[mf][2][reg] * adv[2] + acc[mf][3][reg] * adv[3];
      #pragma unroll
      for (int off = 1; off < 16; off <<= 1){
        sl += __shfl_xor(sl, off);
        sr += __shfl_xor(sr, off);
      }
      int row = m0 + mf * 16 + lq * 4 + reg;
      if (lm == 0 && row < nrows){
        al[(size_t)row * 4 + w] = sl;
        ar[(size_t)row * 4 + w] = sr;
      }
      if (row < nrows){
        ushort4 pk;
        pk.x = __half_as_ushort(__float2half(acc[mf][0][reg]));
        pk.y = __half_as_ushort(__float2half(acc[mf][1][reg]));
        pk.z = __half_as_ushort(__float2half(acc[mf][2][reg]));
        pk.w = __half_as_ushort(__float2half(acc[mf][3][reg]));
        *(ushort4*)(hb + (size_t)row * 256 + w * 64 + lm * 4) = pk;
      }
    }
  }
}

// ---------------- layer-0 per-node softmax + aggregate (wave per node) ----------------
#define AGG_STEP(QV, POFF) { \
    int je = j + (POFF) + eh; \
    float w = wbase[je * 4 + hd]; \
    int4 qq = QV; \
    int jn = je + 8; \
    if (jn < deg){ \
      int s = sbase[jn]; \
      QV = *(const int4*)((const char*)hb + (((unsigned)s << 9) + choff)); \
    } \
    const __half2* h2 = (const __half2*)&qq; \
    float2 f0 = __half22float2(h2[0]); \
    float2 f1 = __half22float2(h2[1]); \
    float2 f2 = __half22float2(h2[2]); \
    float2 f3 = __half22float2(h2[3]); \
    a0 = fmaf(f0.x, w, a0); a1 = fmaf(f0.y, w, a1); \
    a2 = fmaf(f1.x, w, a2); a3 = fmaf(f1.y, w, a3); \
    a4 = fmaf(f2.x, w, a4); a5 = fmaf(f2.y, w, a5); \
    a6 = fmaf(f3.x, w, a6); a7 = fmaf(f3.y, w, a7); \
  }

__global__ __launch_bounds__(256, 8) void k_node(const int* __restrict__ ptr,
    const int* __restrict__ csr, const __half* __restrict__ hb,
    const float* __restrict__ al, const float* __restrict__ ar,
    const float* __restrict__ bias, float* __restrict__ out, int N){
  __shared__ float4 wsm[4][64];
  __shared__ int    ssm[4][64];
  int n = (blockIdx.x * blockDim.x + threadIdx.x) >> 6;
  int lane = threadIdx.x & 63;
  int wv = threadIdx.x >> 6;
  if (n >= N) return;
  int beg = ptr[n], end = ptr[n + 1];
  int deg = end - beg;
  float4 arv = *(const float4*)(ar + (size_t)n * 4);

  if (deg <= 64){
    int idx = beg + lane;
    bool act = idx < end;
    int mye = act ? csr[idx] : 0;
    int eh = lane >> 5;
    int hd = (lane >> 3) & 3;
    int c8 = lane & 7;
    unsigned choff = (unsigned)(hd * 128 + c8 * 16);

    float e0 = -1e30f, e1 = -1e30f, e2 = -1e30f, e3 = -1e30f;
    if (act){
      float4 av = *(const float4*)((const char*)al + ((unsigned)mye << 4));
      e0 = lrelu(av.x + arv.x); e1 = lrelu(av.y + arv.y);
      e2 = lrelu(av.z + arv.z); e3 = lrelu(av.w + arv.w);
    }
    int s0 = __shfl(mye, 0 + eh), s1 = __shfl(mye, 2 + eh);
    int s2 = __shfl(mye, 4 + eh), s3 = __shfl(mye, 6 + eh);
    int4 q0 = *(const int4*)((const char*)hb + (((unsigned)s0 << 9) + choff));
    int4 q1 = *(const int4*)((const char*)hb + (((unsigned)s1 << 9) + choff));
    int4 q2 = *(const int4*)((const char*)hb + (((unsigned)s2 << 9) + choff));
    int4 q3 = *(const int4*)((const char*)hb + (((unsigned)s3 << 9) + choff));

    float m0 = e0, m1 = e1, m2 = e2, m3 = e3;
    #pragma unroll
    for (int off = 32; off > 0; off >>= 1){
      m0 = fmaxf(m0, __shfl_xor(m0, off));
      m1 = fmaxf(m1, __shfl_xor(m1, off));
      m2 = fmaxf(m2, __shfl_xor(m2, off));
      m3 = fmaxf(m3, __shfl_xor(m3, off));
    }
    float w0 = __expf(e0 - m0), w1 = __expf(e1 - m1);
    float w2 = __expf(e2 - m2), w3 = __expf(e3 - m3);
    float d0 = w0, d1 = w1, d2 = w2, d3 = w3;
    #pragma unroll
    for (int off = 32; off > 0; off >>= 1){
      d0 += __shfl_xor(d0, off);
      d1 += __shfl_xor(d1, off);
      d2 += __shfl_xor(d2, off);
      d3 += __shfl_xor(d3, off);
    }
    wsm[wv][lane] = make_float4(w0 / (d0 + EPS_SM), w1 / (d1 + EPS_SM),
                                w2 / (d2 + EPS_SM), w3 / (d3 + EPS_SM));
    ssm[wv][lane] = mye;
    __builtin_amdgcn_wave_barrier();

    const float* wbase = (const float*)&wsm[wv][0];
    const int*   sbase = &ssm[wv][0];
    float a0=0.f,a1=0.f,a2=0.f,a3=0.f,a4=0.f,a5=0.f,a6=0.f,a7=0.f;
    for (int j = 0; j < deg; j += 8){
      AGG_STEP(q0, 0)
      AGG_STEP(q1, 2)
      AGG_STEP(q2, 4)
      AGG_STEP(q3, 6)
    }
    #pragma unroll
    for (int off = 32; off >= 8; off >>= 1){
      a0 += __shfl_xor(a0, off); a1 += __shfl_xor(a1, off);
      a2 += __shfl_xor(a2, off); a3 += __shfl_xor(a3, off);
      a4 += __shfl_xor(a4, off); a5 += __shfl_xor(a5, off);
      a6 += __shfl_xor(a6, off); a7 += __shfl_xor(a7, off);
    }
    if (lane < 8){
      float* op = out + (size_t)n * 64 + c8 * 2;
      float2 b0 = *(const float2*)(bias + 0 * 16 + c8 * 2);
      float2 b1 = *(const float2*)(bias + 1 * 16 + c8 * 2);
      float2 b2 = *(const float2*)(bias + 2 * 16 + c8 * 2);
      float2 b3 = *(const float2*)(bias + 3 * 16 + c8 * 2);
      *(float2*)(op + 0)  = make_float2(a0 * 0.25f + b0.x, a4 * 0.25f + b0.y);
      *(float2*)(op + 16) = make_float2(a1 * 0.25f + b1.x, a5 * 0.25f + b1.y);
      *(float2*)(op + 32) = make_float2(a2 * 0.25f + b2.x, a6 * 0.25f + b2.y);
      *(float2*)(op + 48) = make_float2(a3 * 0.25f + b3.x, a7 * 0.25f + b3.y);
    }
  } else {
    int hd = lane >> 4;
    int t = lane & 15;
    const __half* hbase = hb + hd * 64 + t * 4;
    float ax = 0.f, ay = 0.f, az = 0.f, aw = 0.f;
    float m0 = -1e30f, m1 = -1e30f, m2 = -1e30f, m3 = -1e30f;
    for (int i = beg + lane; i < end; i += 64){
      int s = csr[i];
      float4 av = *(const float4*)(al + (size_t)s * 4);
      m0 = fmaxf(m0, lrelu(av.x + arv.x));
      m1 = fmaxf(m1, lrelu(av.y + arv.y));
      m2 = fmaxf(m2, lrelu(av.z + arv.z));
      m3 = fmaxf(m3, lrelu(av.w + arv.w));
    }
    #pragma unroll
    for (int off = 32; off > 0; off >>= 1){
      m0 = fmaxf(m0, __shfl_xor(m0, off));
      m1 = fmaxf(m1, __shfl_xor(m1, off));
      m2 = fmaxf(m2, __shfl_xor(m2, off));
      m3 = fmaxf(m3, __shfl_xor(m3, off));
    }
    float d0 = 0.f, d1 = 0.f, d2 = 0.f, d3 = 0.f;
    for (int i = beg + lane; i < end; i += 64){
      int s = csr[i];
      float4 av = *(const float4*)(al + (size_t)s * 4);
      d0 += __expf(lrelu(av.x + arv.x) - m0);
      d1 += __expf(lrelu(av.y + arv.y) - m1);
      d2 += __expf(lrelu(av.z + arv.z) - m2);
      d3 += __expf(lrelu(av.w + arv.w) - m3);
    }
    #pragma unroll
    for (int off = 32; off > 0; off >>= 1){
      d0 += __shfl_xor(d0, off);
      d1 += __shfl_xor(d1, off);
      d2 += __shfl_xor(d2, off);
      d3 += __shfl_xor(d3, off);
    }
    float i0 = 1.f / (d0 + EPS_SM), i1 = 1.f / (d1 + EPS_SM);
    float i2 = 1.f / (d2 + EPS_SM), i3 = 1.f / (d3 + EPS_SM);
    float arh = hd == 0 ? arv.x : hd == 1 ? arv.y : hd == 2 ? arv.z : arv.w;
    float mh  = hd == 0 ? m0 : hd == 1 ? m1 : hd == 2 ? m2 : m3;
    float ih  = hd == 0 ? i0 : hd == 1 ? i1 : hd == 2 ? i2 : i3;
    for (int i = beg; i < end; i++){
      int s = csr[i];
      float w = __expf(lrelu(al[(size_t)s * 4 + hd] + arh) - mh) * ih;
      ushort4 u = *(const ushort4*)(hbase + (size_t)s * 256);
      ax = fmaf(__half2float(__ushort_as_half(u.x)), w, ax);
      ay = fmaf(__half2float(__ushort_as_half(u.y)), w, ay);
      az = fmaf(__half2float(__ushort_as_half(u.z)), w, az);
      aw = fmaf(__half2float(__ushort_as_half(u.w)), w, aw);
    }
    #pragma unroll
    for (int off = 16; off <= 32; off <<= 1){
      ax += __shfl_xor(ax, off);
      ay += __shfl_xor(ay, off);
      az += __shfl_xor(az, off);
      aw += __shfl_xor(aw, off);
    }
    if (lane < 16){
      float* op = out + (size_t)n * 64;
      op[t]      = ax * 0.25f + bias[t];
      op[16 + t] = ay * 0.25f + bias[16 + t];
      op[32 + t] = az * 0.25f + bias[32 + t];
      op[48 + t] = aw * 0.25f + bias[48 + t];
    }
  }
}

// ---------------- k_attn: BN+ReLU -> y fp16, al/ar = y @ Va  (16 lanes/node) ----------------
__global__ __launch_bounds__(256) void k_attn(const float* __restrict__ bufA,
    const float* __restrict__ scale, const float* __restrict__ shift,
    const float* __restrict__ va,   // [64][8] : s0..s3,d0..d3
    _Float16* __restrict__ yh, float* __restrict__ al, float* __restrict__ ar, int N){
  int n = (blockIdx.x * 256 + threadIdx.x) >> 4;
  int t = threadIdx.x & 15;
  if (n >= N) return;
  float4 v  = *(const float4*)(bufA + (size_t)n * 64 + t * 4);
  float4 sc = *(const float4*)(scale + t * 4);
  float4 sh = *(const float4*)(shift + t * 4);
  float y0 = fmaxf(fmaf(v.x, sc.x, sh.x), 0.f);
  float y1 = fmaxf(fmaf(v.y, sc.y, sh.y), 0.f);
  float y2 = fmaxf(fmaf(v.z, sc.z, sh.z), 0.f);
  float y3 = fmaxf(fmaf(v.w, sc.w, sh.w), 0.f);
  ushort4 pk;
  pk.x = __half_as_ushort(__float2half(y0));
  pk.y = __half_as_ushort(__float2half(y1));
  pk.z = __half_as_ushort(__float2half(y2));
  pk.w = __half_as_ushort(__float2half(y3));
  *(ushort4*)(yh + (size_t)n * 64 + t * 4) = pk;

  float p0=0,p1=0,p2=0,p3=0,p4=0,p5=0,p6=0,p7=0;
  #define ATT_ACC(YV, J) { \
    const float4 a = *(const float4*)(va + (t * 4 + (J)) * 8); \
    const float4 b = *(const float4*)(va + (t * 4 + (J)) * 8 + 4); \
    p0 = fmaf(YV, a.x, p0); p1 = fmaf(YV, a.y, p1); \
    p2 = fmaf(YV, a.z, p2); p3 = fmaf(YV, a.w, p3); \
    p4 = fmaf(YV, b.x, p4); p5 = fmaf(YV, b.y, p5); \
    p6 = fmaf(YV, b.z, p6); p7 = fmaf(YV, b.w, p7); }
  ATT_ACC(y0, 0) ATT_ACC(y1, 1) ATT_ACC(y2, 2) ATT_ACC(y3, 3)
  #undef ATT_ACC
  #pragma unroll
  for (int off = 1; off < 16; off <<= 1){
    p0 += __shfl_xor(p0, off); p1 += __shfl_xor(p1, off);
    p2 += __shfl_xor(p2, off); p3 += __shfl_xor(p3, off);
    p4 += __shfl_xor(p4, off); p5 += __shfl_xor(p5, off);
    p6 += __shfl_xor(p6, off); p7 += __shfl_xor(p7, off);
  }
  if (t == 0){
    *(float4*)(al + (size_t)n * 4) = make_float4(p0, p1, p2, p3);
    *(float4*)(ar + (size_t)n * 4) = make_float4(p4, p5, p6, p7);
  }
}

// ---------------- k_agg: softmax + aggregate y (64ch) per head -> agg fp16 [N][h*64+c].
// TWO nodes per wave (32 lanes each) when both degs <= 32 (~99.8% of pairs). ----------------
#define AGG_FMA(Q, W4) { \
    union { uint2 u; __half2 h[2]; } _u; _u.u = (Q); \
    float2 _fa = __half22float2(_u.h[0]); \
    float2 _fb = __half22float2(_u.h[1]); \
    a0.x = fmaf(_fa.x, (W4).x, a0.x); a0.y = fmaf(_fa.y, (W4).x, a0.y); \
    a0.z = fmaf(_fb.x, (W4).x, a0.z); a0.w = fmaf(_fb.y, (W4).x, a0.w); \
    a1.x = fmaf(_fa.x, (W4).y, a1.x); a1.y = fmaf(_fa.y, (W4).y, a1.y); \
    a1.z = fmaf(_fb.x, (W4).y, a1.z); a1.w = fmaf(_fb.y, (W4).y, a1.w); \
    a2.x = fmaf(_fa.x, (W4).z, a2.x); a2.y = fmaf(_fa.y, (W4).z, a2.y); \
    a2.z = fmaf(_fb.x, (W4).z, a2.z); a2.w = fmaf(_fb.y, (W4).z, a2.w); \
    a3.x = fmaf(_fa.x, (W4).w, a3.x); a3.y = fmaf(_fa.y, (W4).w, a3.y); \
    a3.z = fmaf(_fb.x, (W4).w, a3.z); a3.w = fmaf(_fb.y, (W4).w, a3.w); \
  }

#define AGG_WRITE(n, t) { \
    char* base = (char*)aggh + ((size_t)(n) << 9) + (t) * 8; \
    ushort4 pk; \
    pk.x = __half_as_ushort(__float2half(a0.x)); \
    pk.y = __half_as_ushort(__float2half(a0.y)); \
    pk.z = __half_as_ushort(__float2half(a0.z)); \
    pk.w = __half_as_ushort(__float2half(a0.w)); \
    *(ushort4*)(base + 0)   = pk; \
    pk.x = __half_as_ushort(__float2half(a1.x)); \
    pk.y = __half_as_ushort(__float2half(a1.y)); \
    pk.z = __half_as_ushort(__float2half(a1.z)); \
    pk.w = __half_as_ushort(__float2half(a1.w)); \
    *(ushort4*)(base + 128) = pk; \
    pk.x = __half_as_ushort(__float2half(a2.x)); \
    pk.y = __half_as_ushort(__float2half(a2.y)); \
    pk.z = __half_as_ushort(__float2half(a2.z)); \
    pk.w = __half_as_ushort(__float2half(a2.w)); \
    *(ushort4*)(base + 256) = pk; \
    pk.x = __half_as_ushort(__float2half(a3.x)); \
    pk.y = __half_as_ushort(__float2half(a3.y)); \
    pk.z = __half_as_ushort(__float2half(a3.z)); \
    pk.w = __half_as_ushort(__float2half(a3.w)); \
    *(ushort4*)(base + 384) = pk; \
  }

__global__ __launch_bounds__(256, 8) void k_agg(const int* __restrict__ ptr,
    const int* __restrict__ csr, const _Float16* __restrict__ yh,
    const float* __restrict__ al, const float* __restrict__ ar,
    __half* __restrict__ aggh, int N){
  __shared__ float4 wsm[4][64];
  __shared__ int    ssm[4][64];
  int lane = threadIdx.x & 63;
  int wv = threadIdx.x >> 6;
  int base = (blockIdx.x * 4 + wv) * 2;
  if (base >= N) return;

  int begA = ptr[base];
  int endA = ptr[base + 1];
  int degA = endA - begA;
  bool dual = (base + 1 < N);
  int endB = dual ? ptr[base + 2] : endA;
  int degB = endB - endA;    // beg of node base+1 is endA (contiguous CSR)

  if (dual && degA <= 32 && degB <= 32){
    // ---------------- fast path: node half h2 = lane>>5 ----------------
    int h2 = lane >> 5;
    int l32 = lane & 31;
    int es = (lane >> 4) & 1;    // edge slot within half
    int t = lane & 15;           // channel quad
    int n = base + h2;
    int beg = h2 ? endA : begA;
    int deg = h2 ? degB : degA;
    float4 arv = *(const float4*)(ar + (size_t)n * 4);

    bool act = l32 < deg;
    int mye = act ? csr[beg + l32] : 0;
    float e0 = -1e30f, e1 = -1e30f, e2 = -1e30f, e3 = -1e30f;
    if (act){
      float4 av = *(const float4*)((const char*)al + ((unsigned)mye << 4));
      e0 = lrelu(av.x + arv.x); e1 = lrelu(av.y + arv.y);
      e2 = lrelu(av.z + arv.z); e3 = lrelu(av.w + arv.w);
    }
    // prefetch edges {es} and {2+es} of this node while the softmax reduces
    int sA = __shfl(mye, h2 * 32 + es);
    int sB = __shfl(mye, h2 * 32 + 2 + es);
    uint2 qA = *(const uint2*)((const char*)yh + (((unsigned)sA) << 7) + t * 8);
    uint2 qB = *(const uint2*)((const char*)yh + (((unsigned)sB) << 7) + t * 8);

    float m0 = e0, m1 = e1, m2 = e2, m3 = e3;
    #pragma unroll
    for (int off = 16; off > 0; off >>= 1){
      m0 = fmaxf(m0, __shfl_xor(m0, off));
      m1 = fmaxf(m1, __shfl_xor(m1, off));
      m2 = fmaxf(m2, __shfl_xor(m2, off));
      m3 = fmaxf(m3, __shfl_xor(m3, off));
    }
    float w0 = __expf(e0 - m0), w1 = __expf(e1 - m1);
    float w2 = __expf(e2 - m2), w3 = __expf(e3 - m3);
    float d0 = w0, d1 = w1, d2 = w2, d3 = w3;
    #pragma unroll
    for (int off = 16; off > 0; off >>= 1){
      d0 += __shfl_xor(d0, off);
      d1 += __shfl_xor(d1, off);
      d2 += __shfl_xor(d2, off);
      d3 += __shfl_xor(d3, off);
    }
    wsm[wv][lane] = make_float4(w0 / (d0 + EPS_SM), w1 / (d1 + EPS_SM),
                                w2 / (d2 + EPS_SM), w3 / (d3 + EPS_SM));
    ssm[wv][lane] = mye;
    __builtin_amdgcn_wave_barrier();

    float4 a0 = {0,0,0,0}, a1 = {0,0,0,0}, a2 = {0,0,0,0}, a3 = {0,0,0,0};
    int lbase = h2 * 32;
    for (int j = 0; j < deg; j += 4){
      uint2 cur = qA;
      if (j + 4 < deg){
        int s2 = ssm[wv][lbase + j + 4 + es];
        qA = *(const uint2*)((const char*)yh + (((unsigned)s2) << 7) + t * 8);
      }
      float4 w4 = wsm[wv][lbase + j + es];
      AGG_FMA(cur, w4)
      uint2 curB = qB;
      if (j + 6 < deg){
        int s3 = ssm[wv][lbase + j + 6 + es];
        qB = *(const uint2*)((const char*)yh + (((unsigned)s3) << 7) + t * 8);
      }
      float4 w4b = wsm[wv][lbase + j + 2 + es];
      AGG_FMA(curB, w4b)
    }
    // combine the 2 edge slots (xor 16 stays within the 32-lane half)
    #define R16(V) { V += __shfl_xor(V, 16); }
    R16(a0.x) R16(a0.y) R16(a0.z) R16(a0.w)
    R16(a1.x) R16(a1.y) R16(a1.z) R16(a1.w)
    R16(a2.x) R16(a2.y) R16(a2.z) R16(a2.w)
    R16(a3.x) R16(a3.y) R16(a3.z) R16(a3.w)
    #undef R16
    if (es == 0) AGG_WRITE(n, t)
    return;
  }

  // ---------------- sequential fallback: full wave per node ----------------
  int nEnd = dual ? base + 2 : base + 1;
  for (int n = base; n < nEnd; n++){
    int beg = ptr[n], end = ptr[n + 1];
    int deg = end - beg;
    float4 arv = *(const float4*)(ar + (size_t)n * 4);
    int eh = lane >> 4;
    int t  = lane & 15;
    float4 a0 = {0,0,0,0}, a1 = {0,0,0,0}, a2 = {0,0,0,0}, a3 = {0,0,0,0};

    if (deg <= 64){
      int idx = beg + lane;
      bool act = idx < end;
      int mye = act ? csr[idx] : 0;
      float e0 = -1e30f, e1 = -1e30f, e2 = -1e30f, e3 = -1e30f;
      if (act){
        float4 av = *(const float4*)((const char*)al + ((unsigned)mye << 4));
        e0 = lrelu(av.x + arv.x); e1 = lrelu(av.y + arv.y);
        e2 = lrelu(av.z + arv.z); e3 = lrelu(av.w + arv.w);
      }
      int sA = __shfl(mye, eh);
      int sB = __shfl(mye, 4 + eh);
      uint2 qA = *(const uint2*)((const char*)yh + (((unsigned)sA) << 7) + t * 8);
      uint2 qB = *(const uint2*)((const char*)yh + (((unsigned)sB) << 7) + t * 8);

      float m0 = e0, m1 = e1, m2 = e2, m3 = e3;
      #pragma unroll
      for (int off = 32; off > 0; off >>= 1){
        m0 = fmaxf(m0, __shfl_xor(m0, off));
        m1 = fmaxf(m1, __shfl_xor(m1, off));
        m2 = fmaxf(m2, __shfl_xor(m2, off));
        m3 = fmaxf(m3, __shfl_xor(m3, off));
      }
      float w0 = __expf(e0 - m0), w1 = __expf(e1 - m1);
      float w2 = __expf(e2 - m2), w3 = __expf(e3 - m3);
      float d0 = w0, d1 = w1, d2 = w2, d3 = w3;
      #pragma unroll
      for (int off = 32; off > 0; off >>= 1){
        d0 += __shfl_xor(d0, off);
        d1 += __shfl_xor(d1, off);
        d2 += __shfl_xor(d2, off);
        d3 += __shfl_xor(d3, off);
      }
      wsm[wv][lane] = make_float4(w0 / (d0 + EPS_SM), w1 / (d1 + EPS_SM),
                                  w2 / (d2 + EPS_SM), w3 / (d3 + EPS_SM));
      ssm[wv][lane] = mye;
      __builtin_amdgcn_wave_barrier();

      for (int j = 0; j < deg; j += 8){
        uint2 cur = qA;
        if (j + 8 < deg){
          int s2 = ssm[wv][j + 8 + eh];
          qA = *(const uint2*)((const char*)yh + (((unsigned)s2) << 7) + t * 8);
        }
        float4 w4 = wsm[wv][j + eh];
        AGG_FMA(cur, w4)
        uint2 curB = qB;
        if (j + 12 < deg){
          int s3 = ssm[wv][j + 12 + eh];
          qB = *(const uint2*)((const char*)yh + (((unsigned)s3) << 7) + t * 8);
        }
        float4 w4b = wsm[wv][j + 4 + eh];
        AGG_FMA(curB, w4b)
      }
      __builtin_amdgcn_wave_barrier();
    } else {
      // rare: deg > 64
      float m0 = -1e30f, m1 = -1e30f, m2 = -1e30f, m3 = -1e30f;
      for (int i = beg + lane; i < end; i += 64){
        int s = csr[i];
        float4 av = *(const float4*)(al + (size_t)s * 4);
        m0 = fmaxf(m0, lrelu(av.x + arv.x));
        m1 = fmaxf(m1, lrelu(av.y + arv.y));
        m2 = fmaxf(m2, lrelu(av.z + arv.z));
        m3 = fmaxf(m3, lrelu(av.w + arv.w));
      }
      #pragma unroll
      for (int off = 32; off > 0; off >>= 1){
        m0 = fmaxf(m0, __shfl_xor(m0, off));
        m1 = fmaxf(m1, __shfl_xor(m1, off));
        m2 = fmaxf(m2, __shfl_xor(m2, off));
        m3 = fmaxf(m3, __shfl_xor(m3, off));
      }
      float d0 = 0.f, d1 = 0.f, d2 = 0.f, d3 = 0.f;
      for (int i = beg + lane; i < end; i += 64){
        int s = csr[i];
        float4 av = *(const float4*)(al + (size_t)s * 4);
        d0 += __expf(lrelu(av.x + arv.x) - m0);
        d1 += __expf(lrelu(av.y + arv.y) - m1);
        d2 += __expf(lrelu(av.z + arv.z) - m2);
        d3 += __expf(lrelu(av.w + arv.w) - m3);
      }
      #pragma unroll
      for (int off = 32; off > 0; off >>= 1){
        d0 += __shfl_xor(d0, off);
        d1 += __shfl_xor(d1, off);
        d2 += __shfl_xor(d2, off);
        d3 += __shfl_xor(d3, off);
      }
      float i0 = 1.f / (d0 + EPS_SM), i1 = 1.f / (d1 + EPS_SM);
      float i2 = 1.f / (d2 + EPS_SM), i3 = 1.f / (d3 + EPS_SM);
      for (int i = beg; i < end; i += 4){
        int ie = i + eh;
        float w0 = 0.f, w1 = 0.f, w2 = 0.f, w3 = 0.f;
        int s = 0;
        if (ie < end){
          s = csr[ie];
          float4 av = *(const float4*)(al + (size_t)s * 4);
          w0 = __expf(lrelu(av.x + arv.x) - m0) * i0;
          w1 = __expf(lrelu(av.y + arv.y) - m1) * i1;
          w2 = __expf(lrelu(av.z + arv.z) - m2) * i2;
          w3 = __expf(lrelu(av.w + arv.w) - m3) * i3;
        }
        uint2 q = *(const uint2*)((const char*)yh + (((unsigned)s) << 7) + t * 8);
        float4 w4 = make_float4(w0, w1, w2, w3);
        AGG_FMA(q, w4)
      }
    }

    // combine the 4 edge-slot groups (lanes t, t+16, t+32, t+48)
    #define RED2(V) { V += __shfl_xor(V, 16); V += __shfl_xor(V, 32); }
    RED2(a0.x) RED2(a0.y) RED2(a0.z) RED2(a0.w)
    RED2(a1.x) RED2(a1.y) RED2(a1.z) RED2(a1.w)
    RED2(a2.x) RED2(a2.y) RED2(a2.z) RED2(a2.w)
    RED2(a3.x) RED2(a3.y) RED2(a3.z) RED2(a3.w)
    #undef RED2
    if (eh == 0) AGG_WRITE(n, t)
    __builtin_amdgcn_wave_barrier();
  }
}

// ---------------- k_gemmp: out[N,64] = agg[N,256] @ Bt^T + bias (MFMA, 256 rows/block) ----------------
__global__ __launch_bounds__(256, 2) void k_gemmp(const _Float16* __restrict__ A,
    const _Float16* __restrict__ Bt,   // [64 cols][256 K]
    const float* __restrict__ bias, float* __restrict__ out, int nrows){
  __shared__ _Float16 Alds[4][257][8];
  __shared__ _Float16 Blds[4][65][8];
  int tid = threadIdx.x;
  int m0 = blockIdx.x * 256;
  int w = tid >> 6, l = tid & 63;
  int lm = l & 15, lq = l >> 4;
  f32x4 acc[4][4] = {};
  for (int k0 = 0; k0 < 256; k0 += 32){
    #pragma unroll
    for (int it = 0; it < 4; it++){
      int gr = m0 + it * 64 + l;
      if (gr < nrows)
        llds16(A + (size_t)gr * 256 + k0 + w * 8, &Alds[w][it * 64][0]);
    }
    llds16(Bt + (size_t)l * 256 + k0 + w * 8, &Blds[w][0][0]);
    __syncthreads();
    half8 af[4];
    #pragma unroll
    for (int mf = 0; mf < 4; mf++) af[mf] = *(const half8*)&Alds[lq][w * 64 + mf * 16 + lm][0];
    #pragma unroll
    for (int j = 0; j < 4; j++){
      half8 bf = *(const half8*)&Blds[lq][j * 16 + lm][0];
      #pragma unroll
      for (int mf = 0; mf < 4; mf++)
        acc[mf][j] = __builtin_amdgcn_mfma_f32_16x16x32_f16(af[mf], bf, acc[mf][j], 0, 0, 0);
    }
    __syncthreads();
  }
  float bv[4];
  #pragma unroll
  for (int j = 0; j < 4; j++) bv[j] = bias[j * 16 + lm];
  #pragma unroll
  for (int mf = 0; mf < 4; mf++){
    #pragma unroll
    for (int reg = 0; reg < 4; reg++){
      int row = m0 + w * 64 + mf * 16 + lq * 4 + reg;
      if (row < nrows){
        #pragma unroll
        for (int j = 0; j < 4; j++)
          out[(size_t)row * 64 + j * 16 + lm] = acc[mf][j][reg] + bv[j];
      }
    }
  }
}

// ---------------- BatchNorm stats + fused finalize -> scale/shift ----------------
__global__ __launch_bounds__(256) void k_bnstats(const float* __restrict__ x, int N,
                                                 float* __restrict__ gsum, float* __restrict__ gsq,
                                                 int* __restrict__ tick,
                                                 const float* __restrict__ g, const float* __restrict__ be,
                                                 float* __restrict__ scale, float* __restrict__ shift){
  int c = threadIdx.x & 63;
  int rg = threadIdx.x >> 6;
  float s = 0.f, q = 0.f;
  for (int r = blockIdx.x * 4 + rg; r < N; r += gridDim.x * 4){
    float v = x[(size_t)r * 64 + c];
    s += v; q += v * v;
  }
  __shared__ float ls[4][64], lq[4][64];
  __shared__ int amLast;
  ls[rg][c] = s; lq[rg][c] = q;
  __syncthreads();
  if (rg == 0){
    s = ls[0][c] + ls[1][c] + ls[2][c] + ls[3][c];
    q = lq[0][c] + lq[1][c] + lq[2][c] + lq[3][c];
    atomicAdd(&gsum[c], s);
    atomicAdd(&gsq[c], q);
  }
  __threadfence();
  if (threadIdx.x == 0)
    amLast = (atomicAdd(tick, 1) == (int)gridDim.x - 1) ? 1 : 0;
  __syncthreads();
  if (amLast && threadIdx.x < 64){
    float gs = atomicAdd(&gsum[c], 0.f);
    float gq = atomicAdd(&gsq[c], 0.f);
    float m = gs / (float)N;
    float v = gq / (float)N - m * m;
    float sc = g[c] * rsqrtf(v + EPS_BN);
    scale[c] = sc;
    shift[c] = be[c] - m * sc;
  }
}

// ---------------- launcher ----------------
extern "C" void kernel_launch(void* const* d_in, const int* in_sizes, int n_in,
                              void* d_out, int out_size, void* d_ws, size_t ws_size,
                              hipStream_t stream){
  const float* x  = (const float*)d_in[0];
  const int*   ei = (const int*)d_in[1];
  const float* W[3]  = {(const float*)d_in[2], (const float*)d_in[6],  (const float*)d_in[10]};
  const float* AS[3] = {(const float*)d_in[3], (const float*)d_in[7],  (const float*)d_in[11]};
  const float* AD[3] = {(const float*)d_in[4], (const float*)d_in[8],  (const float*)d_in[12]};
  const float* BI[3] = {(const float*)d_in[5], (const float*)d_in[9],  (const float*)d_in[13]};
  const float* G[2]  = {(const float*)d_in[14], (const float*)d_in[16]};
  const float* BE[2] = {(const float*)d_in[15], (const float*)d_in[17]};
  const int N = in_sizes[0] / 256;
  const int E = in_sizes[1] / 2;
  const int EN = E + N;

  char* wsb = (char*)d_ws;
  size_t off = 0;
  auto alloc = [&](size_t bytes) -> char* {
    char* p = wsb + off;
    off = (off + bytes + 255) & ~(size_t)255;
    return p;
  };
  int* cnt      = (int*)alloc((size_t)N * 4);
  int* rowptr   = (int*)alloc((size_t)(N + 1) * 4);
  int* part     = (int*)alloc(256 * 4);
  int* cnt2     = (int*)alloc((size_t)N * 4);
  int* csr      = (int*)alloc((size_t)EN * 4);
  _Float16* xh  = (_Float16*)alloc((size_t)N * 256 * 2);
  _Float16* Wt0 = (_Float16*)alloc((size_t)256 * 256 * 2);
  _Float16* Wtp1= (_Float16*)alloc((size_t)64 * 256 * 2);
  _Float16* Wtp2= (_Float16*)alloc((size_t)64 * 256 * 2);
  __half* hb    = (__half*)alloc((size_t)N * 256 * 2);   // layer0 h; reused as agg for layers 1/2
  float* al     = (float*)alloc((size_t)N * 4 * 4);
  float* ar     = (float*)alloc((size_t)N * 4 * 4);
  float* bufA   = (float*)alloc((size_t)N * 64 * 4);
  _Float16* yh  = (_Float16*)alloc((size_t)N * 64 * 2);
  float* va     = (float*)alloc(1024 * 4);               // 2 layers x [64][8]
  float* bn     = (float*)alloc(256 * 4);
  int*   tick   = (int*)alloc(4 * 4);
  float* murs   = (float*)alloc(128 * 4);   // scale[64], shift[64]

  const int chunk = (N + 255) / 256;
  const int n8 = N * 32;
  const int nodeGrid = (N + 3) / 4;
  const int aggGrid = (N + 7) / 8;          // 2 nodes per wave
  const int attnGrid = (N + 15) / 16;
  const int gemmpGrid = (N + 255) / 256;

  hipMemsetAsync(cnt, 0, (size_t)N * 4, stream);
  k_prep1<<<(n8 + 255) / 256, 256, 0, stream>>>(x, xh, n8, ei, E, cnt, cnt2, N,
                                                W[0], W[1], W[2], Wt0, Wtp1, Wtp2,
                                                AS[1], AD[1], AS[2], AD[2], va, bn, tick);
  k_bsumscan<<<256, 256, 0, stream>>>(cnt, N, chunk, part, rowptr, tick + 2);
  k_localscan<<<256, 256, 0, stream>>>(cnt, part, N, chunk, rowptr, csr);

  int gemmGrid = (N + 127) / 128;
  const int FILLB = 1024;   // 128 groups x 8 XCD bins, rank computed on the fly
  // layer 0: gemm fused with XCD-binned csr fill
  k_gemm<0><<<gemmGrid + FILLB, 256, 0, stream>>>(xh, Wt0, AS[0], AD[0], hb, al, ar, N,
                                                  ei, E, cnt2, rowptr, csr, gemmGrid, N);
  k_node<<<nodeGrid, 256, 0, stream>>>(rowptr, csr, hb, al, ar, BI[0], bufA, N);
  k_bnstats<<<256, 256, 0, stream>>>(bufA, N, bn, bn + 64, tick, G[0], BE[0], murs, murs + 64);
  // layer 1: aggregate-then-GEMM (payload = 64-ch y)
  k_attn<<<attnGrid, 256, 0, stream>>>(bufA, murs, murs + 64, va, yh, al, ar, N);
  k_agg<<<aggGrid, 256, 0, stream>>>(rowptr, csr, yh, al, ar, hb, N);
  k_gemmp<<<gemmpGrid, 256, 0, stream>>>((const _Float16*)hb, Wtp1, BI[1], bufA, N);
  k_bnstats<<<256, 256, 0, stream>>>(bufA, N, bn + 128, bn + 192, tick + 1, G[1], BE[1], murs, murs + 64);
  // layer 2
  k_attn<<<attnGrid, 256, 0, stream>>>(bufA, murs, murs + 64, va + 512, yh, al, ar, N);
  k_agg<<<aggGrid, 256, 0, stream>>>(rowptr, csr, yh, al, ar, hb, N);
  k_gemmp<<<gemmpGrid, 256, 0, stream>>>((const _Float16*)hb, Wtp2, BI[2], (float*)d_out, N);
}

// Round 9
// 471.677 us; speedup vs baseline: 1.0428x; 1.0428x over previous
//
#include <hip/hip_runtime.h>
#include <hip/hip_fp16.h>
#include <math.h>

constexpr float NEG_SLOPE = 0.2f;
constexpr float EPS_BN = 1e-5f;
constexpr float EPS_SM = 1e-16f;

typedef _Float16 half8 __attribute__((ext_vector_type(8)));
typedef float f32x4 __attribute__((ext_vector_type(4)));

__device__ __forceinline__ float lrelu(float x){ return x >= 0.f ? x : NEG_SLOPE * x; }

typedef const __attribute__((address_space(1))) unsigned int* gas_u32;
typedef __attribute__((address_space(3))) unsigned int* las_u32;

__device__ __forceinline__ void llds16(const _Float16* g, _Float16* l){
  __builtin_amdgcn_global_load_lds((gas_u32)(const void*)g, (las_u32)(void*)l, 16, 0, 0);
}

// ---------------- prep1: x->fp16, W0 transpose, post-GEMM B for layers 1/2,
// Va, edge hist+rank in ONE atomic pass (rank = return value), bn/tick zeroing ----------------
__global__ void k_prep1(const float* __restrict__ x, _Float16* __restrict__ xh, int n8,
                        const int* __restrict__ ei, int E, int* __restrict__ cnt,
                        int* __restrict__ rank,
                        const float* __restrict__ W0, const float* __restrict__ W1,
                        const float* __restrict__ W2, _Float16* __restrict__ Wt0,
                        _Float16* __restrict__ Wtp1, _Float16* __restrict__ Wtp2,
                        const float* __restrict__ as1, const float* __restrict__ ad1,
                        const float* __restrict__ as2, const float* __restrict__ ad2,
                        float* __restrict__ va,
                        float* __restrict__ bn, int* __restrict__ tick){
  int t = blockIdx.x * blockDim.x + threadIdx.x;
  if (t < n8){
    const float4* p = (const float4*)(x + (size_t)t * 8);
    float4 v0 = p[0], v1 = p[1];
    half8 h = {(_Float16)v0.x, (_Float16)v0.y, (_Float16)v0.z, (_Float16)v0.w,
               (_Float16)v1.x, (_Float16)v1.y, (_Float16)v1.z, (_Float16)v1.w};
    *(half8*)(xh + (size_t)t * 8) = h;
  }
  if (t < E) rank[t] = atomicAdd(&cnt[ei[E + t]], 1);   // hist + rank, single atomic pass
  if (t < 256) bn[t] = 0.f;
  if (t < 4) tick[t] = 0;
  if (t < 65536){
    int c = t & 255, k = t >> 8;
    Wt0[(size_t)c * 256 + k] = (_Float16)W0[(size_t)k * 256 + c];
  } else if (t < 81920){
    // post-GEMM B for layer 1: Wtp1[c][r=h*64+k] = 0.25*W1[k][h*64+c], c<64
    int u = t - 65536; int c = u & 63, r = u >> 6;
    Wtp1[(size_t)c * 256 + r] = (_Float16)(0.25f * W1[(size_t)(r & 63) * 256 + (r >> 6) * 64 + c]);
  } else if (t < 98304){
    int u = t - 81920; int c = u & 63, r = u >> 6;
    Wtp2[(size_t)c * 256 + r] = (_Float16)(0.25f * W2[(size_t)(r & 63) * 256 + (r >> 6) * 64 + c]);
  } else if (t < 99328){
    // Va[layer][j][sd*4+h] = sum_k W[j][h*64+k] * a[h][k]
    int u = t - 98304;
    int layer = u >> 9;
    int sd = (u >> 8) & 1;
    int u2 = u & 255;
    int c = u2 >> 2, h = u2 & 3;
    const float* Wl = layer ? W2 : W1;
    const float* av = layer ? (sd ? ad2 : as2) : (sd ? ad1 : as1);
    float acc = 0.f;
    #pragma unroll 4
    for (int k = 0; k < 64; k++)
      acc += Wl[(size_t)c * 256 + h * 64 + k] * av[h * 64 + k];
    va[layer * 512 + c * 8 + sd * 4 + h] = acc;
  }
}

// ---------------- CSR scans (degree = cnt[i] + 1 for the self-loop) ----------------
__global__ __launch_bounds__(256) void k_bsumscan(const int* __restrict__ cnt, int n, int chunk,
                                                  int* __restrict__ part, int* __restrict__ ptr,
                                                  int* __restrict__ tick){
  __shared__ int s[256];
  __shared__ int amLast;
  int b = blockIdx.x, t = threadIdx.x;
  int lo = b * chunk, hi = min(n, lo + chunk);
  int v = 0;
  for (int i = lo + t; i < hi; i += 256) v += cnt[i] + 1;
  s[t] = v;
  __syncthreads();
  #pragma unroll
  for (int off = 128; off > 0; off >>= 1){
    if (t < off) s[t] += s[t + off];
    __syncthreads();
  }
  if (t == 0) part[b] = s[0];
  __threadfence();
  if (t == 0) amLast = (atomicAdd(tick, 1) == (int)gridDim.x - 1) ? 1 : 0;
  __syncthreads();
  if (amLast){
    int pv = atomicAdd(&part[t], 0);
    s[t] = pv;
    __syncthreads();
    #pragma unroll
    for (int off = 1; off < 256; off <<= 1){
      int u = (t >= off) ? s[t - off] : 0;
      __syncthreads();
      s[t] += u;
      __syncthreads();
    }
    part[t] = s[t] - pv;
    if (t == 255) ptr[n] = s[255];
  }
}

__global__ __launch_bounds__(256) void k_localscan(const int* __restrict__ cnt, const int* __restrict__ part,
                                                   int n, int chunk, int* __restrict__ ptr,
                                                   int* __restrict__ csr_src){
  __shared__ int s[256];
  int b = blockIdx.x, t = threadIdx.x;
  int i = b * chunk + t;
  int c = (t < chunk && i < n) ? cnt[i] : 0;
  int v = (t < chunk && i < n) ? c + 1 : 0;
  s[t] = v;
  __syncthreads();
  #pragma unroll
  for (int off = 1; off < 256; off <<= 1){
    int u = (t >= off) ? s[t - off] : 0;
    __syncthreads();
    s[t] += u;
    __syncthreads();
  }
  if (t < chunk && i < n){
    int ex = part[b] + s[t] - v;
    ptr[i] = ex;
    csr_src[ex + c] = i;     // self-loop after the c ranked edges
  }
}

// ---------------- k_fill: lean standalone CSR fill (no atomics, full occupancy) ----------------
__global__ __launch_bounds__(256) void k_fill(const int* __restrict__ ei, int E,
                                              const int* __restrict__ rank,
                                              const int* __restrict__ rowptr,
                                              int* __restrict__ csr_src){
  int e = blockIdx.x * 256 + threadIdx.x;
  if (e < E){
    int dst = ei[E + e];
    csr_src[rowptr[dst] + rank[e]] = ei[e];
  }
}

// ---------------- layer-0 MFMA GEMM: 128 rows x 256 cols (pure; fill split out) ----------------
template<int LAYER>
__global__ __launch_bounds__(256, 2) void k_gemm(const _Float16* __restrict__ Xh,
    const _Float16* __restrict__ Wt, const float* __restrict__ a_s, const float* __restrict__ a_d,
    __half* __restrict__ hb, float* __restrict__ al, float* __restrict__ ar, int nrows){
  constexpr int K = 256;
  __shared__ _Float16 Alds[4][129][8];
  __shared__ _Float16 Blds[4][257][8];
  int tid = threadIdx.x;
  int m0 = blockIdx.x * 128;
  int w = tid >> 6, l = tid & 63;
  int lm = l & 15, lq = l >> 4;
  f32x4 acc[8][4] = {};

  for (int k0 = 0; k0 < K; k0 += 32){
    #pragma unroll
    for (int it = 0; it < 2; it++){
      int gr = m0 + it * 64 + l;
      if (gr < nrows)
        llds16(Xh + (size_t)gr * K + k0 + w * 8, &Alds[w][it * 64][0]);
    }
    #pragma unroll
    for (int it = 0; it < 4; it++){
      int col = it * 64 + l;
      llds16(Wt + (size_t)col * K + k0 + w * 8, &Blds[w][it * 64][0]);
    }
    __syncthreads();
    half8 af[8];
    #pragma unroll
    for (int mf = 0; mf < 8; mf++) af[mf] = *(const half8*)&Alds[lq][mf * 16 + lm][0];
    #pragma unroll
    for (int j = 0; j < 4; j++){
      half8 bf = *(const half8*)&Blds[lq][(w * 4 + j) * 16 + lm][0];
      #pragma unroll
      for (int mf = 0; mf < 8; mf++)
        acc[mf][j] = __builtin_amdgcn_mfma_f32_16x16x32_f16(af[mf], bf, acc[mf][j], 0, 0, 0);
    }
    __syncthreads();
  }

  float asv[4], adv[4];
  #pragma unroll
  for (int j = 0; j < 4; j++){
    asv[j] = a_s[w * 64 + j * 16 + lm];
    adv[j] = a_d[w * 64 + j * 16 + lm];
  }
  #pragma unroll
  for (int mf = 0; mf < 8; mf++){
    #pragma unroll
    for (int reg = 0; reg < 4; reg++){
      float sl = acc[mf][0][reg] * asv[0] + acc[mf][1][reg] * asv[1]
               + acc[mf][2][reg] * asv[2] + acc[mf][3][reg] * asv[3];
      float sr = acc[mf][0][reg] * adv[0] + acc[mf][1][reg] * adv[1]
               + acc[mf][2][reg] * adv[2] + acc[mf][3][reg] * adv[3];
      #pragma unroll
      for (int off = 1; off < 16; off <<= 1){
        sl += __shfl_xor(sl, off);
        sr += __shfl_xor(sr, off);
      }
      int row = m0 + mf * 16 + lq * 4 + reg;
      if (lm == 0 && row < nrows){
        al[(size_t)row * 4 + w] = sl;
        ar[(size_t)row * 4 + w] = sr;
      }
      if (row < nrows){
        ushort4 pk;
        pk.x = __half_as_ushort(__float2half(acc[mf][0][reg]));
        pk.y = __half_as_ushort(__float2half(acc[mf][1][reg]));
        pk.z = __half_as_ushort(__float2half(acc[mf][2][reg]));
        pk.w = __half_as_ushort(__float2half(acc[mf][3][reg]));
        *(ushort4*)(hb + (size_t)row * 256 + w * 64 + lm * 4) = pk;
      }
    }
  }
}

// ---------------- layer-0 per-node softmax + aggregate (wave per node) ----------------
#define AGG_STEP(QV, POFF) { \
    int je = j + (POFF) + eh; \
    float w = wbase[je * 4 + hd]; \
    int4 qq = QV; \
    int jn = je + 8; \
    if (jn < deg){ \
      int s = sbase[jn]; \
      QV = *(const int4*)((const char*)hb + (((unsigned)s << 9) + choff)); \
    } \
    const __half2* h2 = (const __half2*)&qq; \
    float2 f0 = __half22float2(h2[0]); \
    float2 f1 = __half22float2(h2[1]); \
    float2 f2 = __half22float2(h2[2]); \
    float2 f3 = __half22float2(h2[3]); \
    a0 = fmaf(f0.x, w, a0); a1 = fmaf(f0.y, w, a1); \
    a2 = fmaf(f1.x, w, a2); a3 = fmaf(f1.y, w, a3); \
    a4 = fmaf(f2.x, w, a4); a5 = fmaf(f2.y, w, a5); \
    a6 = fmaf(f3.x, w, a6); a7 = fmaf(f3.y, w, a7); \
  }

__global__ __launch_bounds__(256, 8) void k_node(const int* __restrict__ ptr,
    const int* __restrict__ csr, const __half* __restrict__ hb,
    const float* __restrict__ al, const float* __restrict__ ar,
    const float* __restrict__ bias, float* __restrict__ out, int N){
  __shared__ float4 wsm[4][64];
  __shared__ int    ssm[4][64];
  int n = (blockIdx.x * blockDim.x + threadIdx.x) >> 6;
  int lane = threadIdx.x & 63;
  int wv = threadIdx.x >> 6;
  if (n >= N) return;
  int beg = ptr[n], end = ptr[n + 1];
  int deg = end - beg;
  float4 arv = *(const float4*)(ar + (size_t)n * 4);

  if (deg <= 64){
    int idx = beg + lane;
    bool act = idx < end;
    int mye = act ? csr[idx] : 0;
    int eh = lane >> 5;
    int hd = (lane >> 3) & 3;
    int c8 = lane & 7;
    unsigned choff = (unsigned)(hd * 128 + c8 * 16);

    float e0 = -1e30f, e1 = -1e30f, e2 = -1e30f, e3 = -1e30f;
    if (act){
      float4 av = *(const float4*)((const char*)al + ((unsigned)mye << 4));
      e0 = lrelu(av.x + arv.x); e1 = lrelu(av.y + arv.y);
      e2 = lrelu(av.z + arv.z); e3 = lrelu(av.w + arv.w);
    }
    int s0 = __shfl(mye, 0 + eh), s1 = __shfl(mye, 2 + eh);
    int s2 = __shfl(mye, 4 + eh), s3 = __shfl(mye, 6 + eh);
    int4 q0 = *(const int4*)((const char*)hb + (((unsigned)s0 << 9) + choff));
    int4 q1 = *(const int4*)((const char*)hb + (((unsigned)s1 << 9) + choff));
    int4 q2 = *(const int4*)((const char*)hb + (((unsigned)s2 << 9) + choff));
    int4 q3 = *(const int4*)((const char*)hb + (((unsigned)s3 << 9) + choff));

    float m0 = e0, m1 = e1, m2 = e2, m3 = e3;
    #pragma unroll
    for (int off = 32; off > 0; off >>= 1){
      m0 = fmaxf(m0, __shfl_xor(m0, off));
      m1 = fmaxf(m1, __shfl_xor(m1, off));
      m2 = fmaxf(m2, __shfl_xor(m2, off));
      m3 = fmaxf(m3, __shfl_xor(m3, off));
    }
    float w0 = __expf(e0 - m0), w1 = __expf(e1 - m1);
    float w2 = __expf(e2 - m2), w3 = __expf(e3 - m3);
    float d0 = w0, d1 = w1, d2 = w2, d3 = w3;
    #pragma unroll
    for (int off = 32; off > 0; off >>= 1){
      d0 += __shfl_xor(d0, off);
      d1 += __shfl_xor(d1, off);
      d2 += __shfl_xor(d2, off);
      d3 += __shfl_xor(d3, off);
    }
    wsm[wv][lane] = make_float4(w0 / (d0 + EPS_SM), w1 / (d1 + EPS_SM),
                                w2 / (d2 + EPS_SM), w3 / (d3 + EPS_SM));
    ssm[wv][lane] = mye;
    __builtin_amdgcn_wave_barrier();

    const float* wbase = (const float*)&wsm[wv][0];
    const int*   sbase = &ssm[wv][0];
    float a0=0.f,a1=0.f,a2=0.f,a3=0.f,a4=0.f,a5=0.f,a6=0.f,a7=0.f;
    for (int j = 0; j < deg; j += 8){
      AGG_STEP(q0, 0)
      AGG_STEP(q1, 2)
      AGG_STEP(q2, 4)
      AGG_STEP(q3, 6)
    }
    #pragma unroll
    for (int off = 32; off >= 8; off >>= 1){
      a0 += __shfl_xor(a0, off); a1 += __shfl_xor(a1, off);
      a2 += __shfl_xor(a2, off); a3 += __shfl_xor(a3, off);
      a4 += __shfl_xor(a4, off); a5 += __shfl_xor(a5, off);
      a6 += __shfl_xor(a6, off); a7 += __shfl_xor(a7, off);
    }
    if (lane < 8){
      float* op = out + (size_t)n * 64 + c8 * 2;
      float2 b0 = *(const float2*)(bias + 0 * 16 + c8 * 2);
      float2 b1 = *(const float2*)(bias + 1 * 16 + c8 * 2);
      float2 b2 = *(const float2*)(bias + 2 * 16 + c8 * 2);
      float2 b3 = *(const float2*)(bias + 3 * 16 + c8 * 2);
      *(float2*)(op + 0)  = make_float2(a0 * 0.25f + b0.x, a4 * 0.25f + b0.y);
      *(float2*)(op + 16) = make_float2(a1 * 0.25f + b1.x, a5 * 0.25f + b1.y);
      *(float2*)(op + 32) = make_float2(a2 * 0.25f + b2.x, a6 * 0.25f + b2.y);
      *(float2*)(op + 48) = make_float2(a3 * 0.25f + b3.x, a7 * 0.25f + b3.y);
    }
  } else {
    int hd = lane >> 4;
    int t = lane & 15;
    const __half* hbase = hb + hd * 64 + t * 4;
    float ax = 0.f, ay = 0.f, az = 0.f, aw = 0.f;
    float m0 = -1e30f, m1 = -1e30f, m2 = -1e30f, m3 = -1e30f;
    for (int i = beg + lane; i < end; i += 64){
      int s = csr[i];
      float4 av = *(const float4*)(al + (size_t)s * 4);
      m0 = fmaxf(m0, lrelu(av.x + arv.x));
      m1 = fmaxf(m1, lrelu(av.y + arv.y));
      m2 = fmaxf(m2, lrelu(av.z + arv.z));
      m3 = fmaxf(m3, lrelu(av.w + arv.w));
    }
    #pragma unroll
    for (int off = 32; off > 0; off >>= 1){
      m0 = fmaxf(m0, __shfl_xor(m0, off));
      m1 = fmaxf(m1, __shfl_xor(m1, off));
      m2 = fmaxf(m2, __shfl_xor(m2, off));
      m3 = fmaxf(m3, __shfl_xor(m3, off));
    }
    float d0 = 0.f, d1 = 0.f, d2 = 0.f, d3 = 0.f;
    for (int i = beg + lane; i < end; i += 64){
      int s = csr[i];
      float4 av = *(const float4*)(al + (size_t)s * 4);
      d0 += __expf(lrelu(av.x + arv.x) - m0);
      d1 += __expf(lrelu(av.y + arv.y) - m1);
      d2 += __expf(lrelu(av.z + arv.z) - m2);
      d3 += __expf(lrelu(av.w + arv.w) - m3);
    }
    #pragma unroll
    for (int off = 32; off > 0; off >>= 1){
      d0 += __shfl_xor(d0, off);
      d1 += __shfl_xor(d1, off);
      d2 += __shfl_xor(d2, off);
      d3 += __shfl_xor(d3, off);
    }
    float i0 = 1.f / (d0 + EPS_SM), i1 = 1.f / (d1 + EPS_SM);
    float i2 = 1.f / (d2 + EPS_SM), i3 = 1.f / (d3 + EPS_SM);
    float arh = hd == 0 ? arv.x : hd == 1 ? arv.y : hd == 2 ? arv.z : arv.w;
    float mh  = hd == 0 ? m0 : hd == 1 ? m1 : hd == 2 ? m2 : m3;
    float ih  = hd == 0 ? i0 : hd == 1 ? i1 : hd == 2 ? i2 : i3;
    for (int i = beg; i < end; i++){
      int s = csr[i];
      float w = __expf(lrelu(al[(size_t)s * 4 + hd] + arh) - mh) * ih;
      ushort4 u = *(const ushort4*)(hbase + (size_t)s * 256);
      ax = fmaf(__half2float(__ushort_as_half(u.x)), w, ax);
      ay = fmaf(__half2float(__ushort_as_half(u.y)), w, ay);
      az = fmaf(__half2float(__ushort_as_half(u.z)), w, az);
      aw = fmaf(__half2float(__ushort_as_half(u.w)), w, aw);
    }
    #pragma unroll
    for (int off = 16; off <= 32; off <<= 1){
      ax += __shfl_xor(ax, off);
      ay += __shfl_xor(ay, off);
      az += __shfl_xor(az, off);
      aw += __shfl_xor(aw, off);
    }
    if (lane < 16){
      float* op = out + (size_t)n * 64;
      op[t]      = ax * 0.25f + bias[t];
      op[16 + t] = ay * 0.25f + bias[16 + t];
      op[32 + t] = az * 0.25f + bias[32 + t];
      op[48 + t] = aw * 0.25f + bias[48 + t];
    }
  }
}

// ---------------- k_attn: BN+ReLU -> y fp16, al/ar = y @ Va  (16 lanes/node) ----------------
__global__ __launch_bounds__(256) void k_attn(const float* __restrict__ bufA,
    const float* __restrict__ scale, const float* __restrict__ shift,
    const float* __restrict__ va,   // [64][8] : s0..s3,d0..d3
    _Float16* __restrict__ yh, float* __restrict__ al, float* __restrict__ ar, int N){
  int n = (blockIdx.x * 256 + threadIdx.x) >> 4;
  int t = threadIdx.x & 15;
  if (n >= N) return;
  float4 v  = *(const float4*)(bufA + (size_t)n * 64 + t * 4);
  float4 sc = *(const float4*)(scale + t * 4);
  float4 sh = *(const float4*)(shift + t * 4);
  float y0 = fmaxf(fmaf(v.x, sc.x, sh.x), 0.f);
  float y1 = fmaxf(fmaf(v.y, sc.y, sh.y), 0.f);
  float y2 = fmaxf(fmaf(v.z, sc.z, sh.z), 0.f);
  float y3 = fmaxf(fmaf(v.w, sc.w, sh.w), 0.f);
  ushort4 pk;
  pk.x = __half_as_ushort(__float2half(y0));
  pk.y = __half_as_ushort(__float2half(y1));
  pk.z = __half_as_ushort(__float2half(y2));
  pk.w = __half_as_ushort(__float2half(y3));
  *(ushort4*)(yh + (size_t)n * 64 + t * 4) = pk;

  float p0=0,p1=0,p2=0,p3=0,p4=0,p5=0,p6=0,p7=0;
  #define ATT_ACC(YV, J) { \
    const float4 a = *(const float4*)(va + (t * 4 + (J)) * 8); \
    const float4 b = *(const float4*)(va + (t * 4 + (J)) * 8 + 4); \
    p0 = fmaf(YV, a.x, p0); p1 = fmaf(YV, a.y, p1); \
    p2 = fmaf(YV, a.z, p2); p3 = fmaf(YV, a.w, p3); \
    p4 = fmaf(YV, b.x, p4); p5 = fmaf(YV, b.y, p5); \
    p6 = fmaf(YV, b.z, p6); p7 = fmaf(YV, b.w, p7); }
  ATT_ACC(y0, 0) ATT_ACC(y1, 1) ATT_ACC(y2, 2) ATT_ACC(y3, 3)
  #undef ATT_ACC
  #pragma unroll
  for (int off = 1; off < 16; off <<= 1){
    p0 += __shfl_xor(p0, off); p1 += __shfl_xor(p1, off);
    p2 += __shfl_xor(p2, off); p3 += __shfl_xor(p3, off);
    p4 += __shfl_xor(p4, off); p5 += __shfl_xor(p5, off);
    p6 += __shfl_xor(p6, off); p7 += __shfl_xor(p7, off);
  }
  if (t == 0){
    *(float4*)(al + (size_t)n * 4) = make_float4(p0, p1, p2, p3);
    *(float4*)(ar + (size_t)n * 4) = make_float4(p4, p5, p6, p7);
  }
}

// ---------------- k_agg: softmax + aggregate y (64ch) per head -> agg fp16 [N][h*64+c].
// TWO nodes per wave (32 lanes each) when both degs <= 32 (~99.8% of pairs). ----------------
#define AGG_FMA(Q, W4) { \
    union { uint2 u; __half2 h[2]; } _u; _u.u = (Q); \
    float2 _fa = __half22float2(_u.h[0]); \
    float2 _fb = __half22float2(_u.h[1]); \
    a0.x = fmaf(_fa.x, (W4).x, a0.x); a0.y = fmaf(_fa.y, (W4).x, a0.y); \
    a0.z = fmaf(_fb.x, (W4).x, a0.z); a0.w = fmaf(_fb.y, (W4).x, a0.w); \
    a1.x = fmaf(_fa.x, (W4).y, a1.x); a1.y = fmaf(_fa.y, (W4).y, a1.y); \
    a1.z = fmaf(_fb.x, (W4).y, a1.z); a1.w = fmaf(_fb.y, (W4).y, a1.w); \
    a2.x = fmaf(_fa.x, (W4).z, a2.x); a2.y = fmaf(_fa.y, (W4).z, a2.y); \
    a2.z = fmaf(_fb.x, (W4).z, a2.z); a2.w = fmaf(_fb.y, (W4).z, a2.w); \
    a3.x = fmaf(_fa.x, (W4).w, a3.x); a3.y = fmaf(_fa.y, (W4).w, a3.y); \
    a3.z = fmaf(_fb.x, (W4).w, a3.z); a3.w = fmaf(_fb.y, (W4).w, a3.w); \
  }

#define AGG_WRITE(n, t) { \
    char* base = (char*)aggh + ((size_t)(n) << 9) + (t) * 8; \
    ushort4 pk; \
    pk.x = __half_as_ushort(__float2half(a0.x)); \
    pk.y = __half_as_ushort(__float2half(a0.y)); \
    pk.z = __half_as_ushort(__float2half(a0.z)); \
    pk.w = __half_as_ushort(__float2half(a0.w)); \
    *(ushort4*)(base + 0)   = pk; \
    pk.x = __half_as_ushort(__float2half(a1.x)); \
    pk.y = __half_as_ushort(__float2half(a1.y)); \
    pk.z = __half_as_ushort(__float2half(a1.z)); \
    pk.w = __half_as_ushort(__float2half(a1.w)); \
    *(ushort4*)(base + 128) = pk; \
    pk.x = __half_as_ushort(__float2half(a2.x)); \
    pk.y = __half_as_ushort(__float2half(a2.y)); \
    pk.z = __half_as_ushort(__float2half(a2.z)); \
    pk.w = __half_as_ushort(__float2half(a2.w)); \
    *(ushort4*)(base + 256) = pk; \
    pk.x = __half_as_ushort(__float2half(a3.x)); \
    pk.y = __half_as_ushort(__float2half(a3.y)); \
    pk.z = __half_as_ushort(__float2half(a3.z)); \
    pk.w = __half_as_ushort(__float2half(a3.w)); \
    *(ushort4*)(base + 384) = pk; \
  }

__global__ __launch_bounds__(256, 8) void k_agg(const int* __restrict__ ptr,
    const int* __restrict__ csr, const _Float16* __restrict__ yh,
    const float* __restrict__ al, const float* __restrict__ ar,
    __half* __restrict__ aggh, int N){
  __shared__ float4 wsm[4][64];
  __shared__ int    ssm[4][64];
  int lane = threadIdx.x & 63;
  int wv = threadIdx.x >> 6;
  int base = (blockIdx.x * 4 + wv) * 2;
  if (base >= N) return;

  int begA = ptr[base];
  int endA = ptr[base + 1];
  int degA = endA - begA;
  bool dual = (base + 1 < N);
  int endB = dual ? ptr[base + 2] : endA;
  int degB = endB - endA;    // beg of node base+1 is endA (contiguous CSR)

  if (dual && degA <= 32 && degB <= 32){
    // ---------------- fast path: node half h2 = lane>>5 ----------------
    int h2 = lane >> 5;
    int l32 = lane & 31;
    int es = (lane >> 4) & 1;    // edge slot within half
    int t = lane & 15;           // channel quad
    int n = base + h2;
    int beg = h2 ? endA : begA;
    int deg = h2 ? degB : degA;
    float4 arv = *(const float4*)(ar + (size_t)n * 4);

    bool act = l32 < deg;
    int mye = act ? csr[beg + l32] : 0;
    float e0 = -1e30f, e1 = -1e30f, e2 = -1e30f, e3 = -1e30f;
    if (act){
      float4 av = *(const float4*)((const char*)al + ((unsigned)mye << 4));
      e0 = lrelu(av.x + arv.x); e1 = lrelu(av.y + arv.y);
      e2 = lrelu(av.z + arv.z); e3 = lrelu(av.w + arv.w);
    }
    // prefetch edges {es} and {2+es} of this node while the softmax reduces
    int sA = __shfl(mye, h2 * 32 + es);
    int sB = __shfl(mye, h2 * 32 + 2 + es);
    uint2 qA = *(const uint2*)((const char*)yh + (((unsigned)sA) << 7) + t * 8);
    uint2 qB = *(const uint2*)((const char*)yh + (((unsigned)sB) << 7) + t * 8);

    float m0 = e0, m1 = e1, m2 = e2, m3 = e3;
    #pragma unroll
    for (int off = 16; off > 0; off >>= 1){
      m0 = fmaxf(m0, __shfl_xor(m0, off));
      m1 = fmaxf(m1, __shfl_xor(m1, off));
      m2 = fmaxf(m2, __shfl_xor(m2, off));
      m3 = fmaxf(m3, __shfl_xor(m3, off));
    }
    float w0 = __expf(e0 - m0), w1 = __expf(e1 - m1);
    float w2 = __expf(e2 - m2), w3 = __expf(e3 - m3);
    float d0 = w0, d1 = w1, d2 = w2, d3 = w3;
    #pragma unroll
    for (int off = 16; off > 0; off >>= 1){
      d0 += __shfl_xor(d0, off);
      d1 += __shfl_xor(d1, off);
      d2 += __shfl_xor(d2, off);
      d3 += __shfl_xor(d3, off);
    }
    wsm[wv][lane] = make_float4(w0 / (d0 + EPS_SM), w1 / (d1 + EPS_SM),
                                w2 / (d2 + EPS_SM), w3 / (d3 + EPS_SM));
    ssm[wv][lane] = mye;
    __builtin_amdgcn_wave_barrier();

    float4 a0 = {0,0,0,0}, a1 = {0,0,0,0}, a2 = {0,0,0,0}, a3 = {0,0,0,0};
    int lbase = h2 * 32;
    for (int j = 0; j < deg; j += 4){
      uint2 cur = qA;
      if (j + 4 < deg){
        int s2 = ssm[wv][lbase + j + 4 + es];
        qA = *(const uint2*)((const char*)yh + (((unsigned)s2) << 7) + t * 8);
      }
      float4 w4 = wsm[wv][lbase + j + es];
      AGG_FMA(cur, w4)
      uint2 curB = qB;
      if (j + 6 < deg){
        int s3 = ssm[wv][lbase + j + 6 + es];
        qB = *(const uint2*)((const char*)yh + (((unsigned)s3) << 7) + t * 8);
      }
      float4 w4b = wsm[wv][lbase + j + 2 + es];
      AGG_FMA(curB, w4b)
    }
    // combine the 2 edge slots (xor 16 stays within the 32-lane half)
    #define R16(V) { V += __shfl_xor(V, 16); }
    R16(a0.x) R16(a0.y) R16(a0.z) R16(a0.w)
    R16(a1.x) R16(a1.y) R16(a1.z) R16(a1.w)
    R16(a2.x) R16(a2.y) R16(a2.z) R16(a2.w)
    R16(a3.x) R16(a3.y) R16(a3.z) R16(a3.w)
    #undef R16
    if (es == 0) AGG_WRITE(n, t)
    return;
  }

  // ---------------- sequential fallback: full wave per node ----------------
  int nEnd = dual ? base + 2 : base + 1;
  for (int n = base; n < nEnd; n++){
    int beg = ptr[n], end = ptr[n + 1];
    int deg = end - beg;
    float4 arv = *(const float4*)(ar + (size_t)n * 4);
    int eh = lane >> 4;
    int t  = lane & 15;
    float4 a0 = {0,0,0,0}, a1 = {0,0,0,0}, a2 = {0,0,0,0}, a3 = {0,0,0,0};

    if (deg <= 64){
      int idx = beg + lane;
      bool act = idx < end;
      int mye = act ? csr[idx] : 0;
      float e0 = -1e30f, e1 = -1e30f, e2 = -1e30f, e3 = -1e30f;
      if (act){
        float4 av = *(const float4*)((const char*)al + ((unsigned)mye << 4));
        e0 = lrelu(av.x + arv.x); e1 = lrelu(av.y + arv.y);
        e2 = lrelu(av.z + arv.z); e3 = lrelu(av.w + arv.w);
      }
      int sA = __shfl(mye, eh);
      int sB = __shfl(mye, 4 + eh);
      uint2 qA = *(const uint2*)((const char*)yh + (((unsigned)sA) << 7) + t * 8);
      uint2 qB = *(const uint2*)((const char*)yh + (((unsigned)sB) << 7) + t * 8);

      float m0 = e0, m1 = e1, m2 = e2, m3 = e3;
      #pragma unroll
      for (int off = 32; off > 0; off >>= 1){
        m0 = fmaxf(m0, __shfl_xor(m0, off));
        m1 = fmaxf(m1, __shfl_xor(m1, off));
        m2 = fmaxf(m2, __shfl_xor(m2, off));
        m3 = fmaxf(m3, __shfl_xor(m3, off));
      }
      float w0 = __expf(e0 - m0), w1 = __expf(e1 - m1);
      float w2 = __expf(e2 - m2), w3 = __expf(e3 - m3);
      float d0 = w0, d1 = w1, d2 = w2, d3 = w3;
      #pragma unroll
      for (int off = 32; off > 0; off >>= 1){
        d0 += __shfl_xor(d0, off);
        d1 += __shfl_xor(d1, off);
        d2 += __shfl_xor(d2, off);
        d3 += __shfl_xor(d3, off);
      }
      wsm[wv][lane] = make_float4(w0 / (d0 + EPS_SM), w1 / (d1 + EPS_SM),
                                  w2 / (d2 + EPS_SM), w3 / (d3 + EPS_SM));
      ssm[wv][lane] = mye;
      __builtin_amdgcn_wave_barrier();

      for (int j = 0; j < deg; j += 8){
        uint2 cur = qA;
        if (j + 8 < deg){
          int s2 = ssm[wv][j + 8 + eh];
          qA = *(const uint2*)((const char*)yh + (((unsigned)s2) << 7) + t * 8);
        }
        float4 w4 = wsm[wv][j + eh];
        AGG_FMA(cur, w4)
        uint2 curB = qB;
        if (j + 12 < deg){
          int s3 = ssm[wv][j + 12 + eh];
          qB = *(const uint2*)((const char*)yh + (((unsigned)s3) << 7) + t * 8);
        }
        float4 w4b = wsm[wv][j + 4 + eh];
        AGG_FMA(curB, w4b)
      }
      __builtin_amdgcn_wave_barrier();
    } else {
      // rare: deg > 64
      float m0 = -1e30f, m1 = -1e30f, m2 = -1e30f, m3 = -1e30f;
      for (int i = beg + lane; i < end; i += 64){
        int s = csr[i];
        float4 av = *(const float4*)(al + (size_t)s * 4);
        m0 = fmaxf(m0, lrelu(av.x + arv.x));
        m1 = fmaxf(m1, lrelu(av.y + arv.y));
        m2 = fmaxf(m2, lrelu(av.z + arv.z));
        m3 = fmaxf(m3, lrelu(av.w + arv.w));
      }
      #pragma unroll
      for (int off = 32; off > 0; off >>= 1){
        m0 = fmaxf(m0, __shfl_xor(m0, off));
        m1 = fmaxf(m1, __shfl_xor(m1, off));
        m2 = fmaxf(m2, __shfl_xor(m2, off));
        m3 = fmaxf(m3, __shfl_xor(m3, off));
      }
      float d0 = 0.f, d1 = 0.f, d2 = 0.f, d3 = 0.f;
      for (int i = beg + lane; i < end; i += 64){
        int s = csr[i];
        float4 av = *(const float4*)(al + (size_t)s * 4);
        d0 += __expf(lrelu(av.x + arv.x) - m0);
        d1 += __expf(lrelu(av.y + arv.y) - m1);
        d2 += __expf(lrelu(av.z + arv.z) - m2);
        d3 += __expf(lrelu(av.w + arv.w) - m3);
      }
      #pragma unroll
      for (int off = 32; off > 0; off >>= 1){
        d0 += __shfl_xor(d0, off);
        d1 += __shfl_xor(d1, off);
        d2 += __shfl_xor(d2, off);
        d3 += __shfl_xor(d3, off);
      }
      float i0 = 1.f / (d0 + EPS_SM), i1 = 1.f / (d1 + EPS_SM);
      float i2 = 1.f / (d2 + EPS_SM), i3 = 1.f / (d3 + EPS_SM);
      for (int i = beg; i < end; i += 4){
        int ie = i + eh;
        float w0 = 0.f, w1 = 0.f, w2 = 0.f, w3 = 0.f;
        int s = 0;
        if (ie < end){
          s = csr[ie];
          float4 av = *(const float4*)(al + (size_t)s * 4);
          w0 = __expf(lrelu(av.x + arv.x) - m0) * i0;
          w1 = __expf(lrelu(av.y + arv.y) - m1) * i1;
          w2 = __expf(lrelu(av.z + arv.z) - m2) * i2;
          w3 = __expf(lrelu(av.w + arv.w) - m3) * i3;
        }
        uint2 q = *(const uint2*)((const char*)yh + (((unsigned)s) << 7) + t * 8);
        float4 w4 = make_float4(w0, w1, w2, w3);
        AGG_FMA(q, w4)
      }
    }

    // combine the 4 edge-slot groups (lanes t, t+16, t+32, t+48)
    #define RED2(V) { V += __shfl_xor(V, 16); V += __shfl_xor(V, 32); }
    RED2(a0.x) RED2(a0.y) RED2(a0.z) RED2(a0.w)
    RED2(a1.x) RED2(a1.y) RED2(a1.z) RED2(a1.w)
    RED2(a2.x) RED2(a2.y) RED2(a2.z) RED2(a2.w)
    RED2(a3.x) RED2(a3.y) RED2(a3.z) RED2(a3.w)
    #undef RED2
    if (eh == 0) AGG_WRITE(n, t)
    __builtin_amdgcn_wave_barrier();
  }
}

// ---------------- k_gemmp: out[N,64] = agg[N,256] @ Bt^T + bias (MFMA, 256 rows/block) ----------------
__global__ __launch_bounds__(256, 2) void k_gemmp(const _Float16* __restrict__ A,
    const _Float16* __restrict__ Bt,   // [64 cols][256 K]
    const float* __restrict__ bias, float* __restrict__ out, int nrows){
  __shared__ _Float16 Alds[4][257][8];
  __shared__ _Float16 Blds[4][65][8];
  int tid = threadIdx.x;
  int m0 = blockIdx.x * 256;
  int w = tid >> 6, l = tid & 63;
  int lm = l & 15, lq = l >> 4;
  f32x4 acc[4][4] = {};
  for (int k0 = 0; k0 < 256; k0 += 32){
    #pragma unroll
    for (int it = 0; it < 4; it++){
      int gr = m0 + it * 64 + l;
      if (gr < nrows)
        llds16(A + (size_t)gr * 256 + k0 + w * 8, &Alds[w][it * 64][0]);
    }
    llds16(Bt + (size_t)l * 256 + k0 + w * 8, &Blds[w][0][0]);
    __syncthreads();
    half8 af[4];
    #pragma unroll
    for (int mf = 0; mf < 4; mf++) af[mf] = *(const half8*)&Alds[lq][w * 64 + mf * 16 + lm][0];
    #pragma unroll
    for (int j = 0; j < 4; j++){
      half8 bf = *(const half8*)&Blds[lq][j * 16 + lm][0];
      #pragma unroll
      for (int mf = 0; mf < 4; mf++)
        acc[mf][j] = __builtin_amdgcn_mfma_f32_16x16x32_f16(af[mf], bf, acc[mf][j], 0, 0, 0);
    }
    __syncthreads();
  }
  float bv[4];
  #pragma unroll
  for (int j = 0; j < 4; j++) bv[j] = bias[j * 16 + lm];
  #pragma unroll
  for (int mf = 0; mf < 4; mf++){
    #pragma unroll
    for (int reg = 0; reg < 4; reg++){
      int row = m0 + w * 64 + mf * 16 + lq * 4 + reg;
      if (row < nrows){
        #pragma unroll
        for (int j = 0; j < 4; j++)
          out[(size_t)row * 64 + j * 16 + lm] = acc[mf][j][reg] + bv[j];
      }
    }
  }
}

// ---------------- BatchNorm stats + fused finalize -> scale/shift ----------------
__global__ __launch_bounds__(256) void k_bnstats(const float* __restrict__ x, int N,
                                                 float* __restrict__ gsum, float* __restrict__ gsq,
                                                 int* __restrict__ tick,
                                                 const float* __restrict__ g, const float* __restrict__ be,
                                                 float* __restrict__ scale, float* __restrict__ shift){
  int c = threadIdx.x & 63;
  int rg = threadIdx.x >> 6;
  float s = 0.f, q = 0.f;
  for (int r = blockIdx.x * 4 + rg; r < N; r += gridDim.x * 4){
    float v = x[(size_t)r * 64 + c];
    s += v; q += v * v;
  }
  __shared__ float ls[4][64], lq[4][64];
  __shared__ int amLast;
  ls[rg][c] = s; lq[rg][c] = q;
  __syncthreads();
  if (rg == 0){
    s = ls[0][c] + ls[1][c] + ls[2][c] + ls[3][c];
    q = lq[0][c] + lq[1][c] + lq[2][c] + lq[3][c];
    atomicAdd(&gsum[c], s);
    atomicAdd(&gsq[c], q);
  }
  __threadfence();
  if (threadIdx.x == 0)
    amLast = (atomicAdd(tick, 1) == (int)gridDim.x - 1) ? 1 : 0;
  __syncthreads();
  if (amLast && threadIdx.x < 64){
    float gs = atomicAdd(&gsum[c], 0.f);
    float gq = atomicAdd(&gsq[c], 0.f);
    float m = gs / (float)N;
    float v = gq / (float)N - m * m;
    float sc = g[c] * rsqrtf(v + EPS_BN);
    scale[c] = sc;
    shift[c] = be[c] - m * sc;
  }
}

// ---------------- launcher ----------------
extern "C" void kernel_launch(void* const* d_in, const int* in_sizes, int n_in,
                              void* d_out, int out_size, void* d_ws, size_t ws_size,
                              hipStream_t stream){
  const float* x  = (const float*)d_in[0];
  const int*   ei = (const int*)d_in[1];
  const float* W[3]  = {(const float*)d_in[2], (const float*)d_in[6],  (const float*)d_in[10]};
  const float* AS[3] = {(const float*)d_in[3], (const float*)d_in[7],  (const float*)d_in[11]};
  const float* AD[3] = {(const float*)d_in[4], (const float*)d_in[8],  (const float*)d_in[12]};
  const float* BI[3] = {(const float*)d_in[5], (const float*)d_in[9],  (const float*)d_in[13]};
  const float* G[2]  = {(const float*)d_in[14], (const float*)d_in[16]};
  const float* BE[2] = {(const float*)d_in[15], (const float*)d_in[17]};
  const int N = in_sizes[0] / 256;
  const int E = in_sizes[1] / 2;
  const int EN = E + N;

  char* wsb = (char*)d_ws;
  size_t off = 0;
  auto alloc = [&](size_t bytes) -> char* {
    char* p = wsb + off;
    off = (off + bytes + 255) & ~(size_t)255;
    return p;
  };
  int* cnt      = (int*)alloc((size_t)N * 4);
  int* rowptr   = (int*)alloc((size_t)(N + 1) * 4);
  int* part     = (int*)alloc(256 * 4);
  int* rank     = (int*)alloc((size_t)E * 4);
  int* csr      = (int*)alloc((size_t)EN * 4);
  _Float16* xh  = (_Float16*)alloc((size_t)N * 256 * 2);
  _Float16* Wt0 = (_Float16*)alloc((size_t)256 * 256 * 2);
  _Float16* Wtp1= (_Float16*)alloc((size_t)64 * 256 * 2);
  _Float16* Wtp2= (_Float16*)alloc((size_t)64 * 256 * 2);
  __half* hb    = (__half*)alloc((size_t)N * 256 * 2);   // layer0 h; reused as agg for layers 1/2
  float* al     = (float*)alloc((size_t)N * 4 * 4);
  float* ar     = (float*)alloc((size_t)N * 4 * 4);
  float* bufA   = (float*)alloc((size_t)N * 64 * 4);
  _Float16* yh  = (_Float16*)alloc((size_t)N * 64 * 2);
  float* va     = (float*)alloc(1024 * 4);               // 2 layers x [64][8]
  float* bn     = (float*)alloc(256 * 4);
  int*   tick   = (int*)alloc(4 * 4);
  float* murs   = (float*)alloc(128 * 4);   // scale[64], shift[64]

  const int chunk = (N + 255) / 256;
  const int n8 = N * 32;
  const int nodeGrid = (N + 3) / 4;
  const int aggGrid = (N + 7) / 8;          // 2 nodes per wave
  const int attnGrid = (N + 15) / 16;
  const int gemmpGrid = (N + 255) / 256;

  hipMemsetAsync(cnt, 0, (size_t)N * 4, stream);
  k_prep1<<<(n8 + 255) / 256, 256, 0, stream>>>(x, xh, n8, ei, E, cnt, rank,
                                                W[0], W[1], W[2], Wt0, Wtp1, Wtp2,
                                                AS[1], AD[1], AS[2], AD[2], va, bn, tick);
  k_bsumscan<<<256, 256, 0, stream>>>(cnt, N, chunk, part, rowptr, tick + 2);
  k_localscan<<<256, 256, 0, stream>>>(cnt, part, N, chunk, rowptr, csr);

  int gemmGrid = (N + 127) / 128;
  // layer 0: pure GEMM; CSR fill as lean standalone kernel (full occupancy)
  k_gemm<0><<<gemmGrid, 256, 0, stream>>>(xh, Wt0, AS[0], AD[0], hb, al, ar, N);
  k_fill<<<(E + 255) / 256, 256, 0, stream>>>(ei, E, rank, rowptr, csr);
  k_node<<<nodeGrid, 256, 0, stream>>>(rowptr, csr, hb, al, ar, BI[0], bufA, N);
  k_bnstats<<<256, 256, 0, stream>>>(bufA, N, bn, bn + 64, tick, G[0], BE[0], murs, murs + 64);
  // layer 1: aggregate-then-GEMM (payload = 64-ch y)
  k_attn<<<attnGrid, 256, 0, stream>>>(bufA, murs, murs + 64, va, yh, al, ar, N);
  k_agg<<<aggGrid, 256, 0, stream>>>(rowptr, csr, yh, al, ar, hb, N);
  k_gemmp<<<gemmpGrid, 256, 0, stream>>>((const _Float16*)hb, Wtp1, BI[1], bufA, N);
  k_bnstats<<<256, 256, 0, stream>>>(bufA, N, bn + 128, bn + 192, tick + 1, G[1], BE[1], murs, murs + 64);
  // layer 2
  k_attn<<<attnGrid, 256, 0, stream>>>(bufA, murs, murs + 64, va + 512, yh, al, ar, N);
  k_agg<<<aggGrid, 256, 0, stream>>>(rowptr, csr, yh, al, ar, hb, N);
  k_gemmp<<<gemmpGrid, 256, 0, stream>>>((const _Float16*)hb, Wtp2, BI[2], (float*)d_out, N);
}

// Round 10
// 464.072 us; speedup vs baseline: 1.0599x; 1.0164x over previous
//
#include <hip/hip_runtime.h>
#include <hip/hip_fp16.h>
#include <math.h>

constexpr float NEG_SLOPE = 0.2f;
constexpr float EPS_BN = 1e-5f;
constexpr float EPS_SM = 1e-16f;

typedef _Float16 half8 __attribute__((ext_vector_type(8)));
typedef float f32x4 __attribute__((ext_vector_type(4)));

__device__ __forceinline__ float lrelu(float x){ return x >= 0.f ? x : NEG_SLOPE * x; }

typedef const __attribute__((address_space(1))) unsigned int* gas_u32;
typedef __attribute__((address_space(3))) unsigned int* las_u32;

__device__ __forceinline__ void llds16(const _Float16* g, _Float16* l){
  __builtin_amdgcn_global_load_lds((gas_u32)(const void*)g, (las_u32)(void*)l, 16, 0, 0);
}

// ---------------- prep1: x->fp16, W0 transpose, post-GEMM B for layers 1/2,
// Va, edge hist+rank in ONE atomic pass over 8-WAY-SHARDED counters
// (cnt8[dst*8 + (e&7)] — 8x fewer serialized RMWs per cache line) ----------------
__global__ void k_prep1(const float* __restrict__ x, _Float16* __restrict__ xh, int n8,
                        const int* __restrict__ ei, int E, int* __restrict__ cnt8,
                        int* __restrict__ rank,
                        const float* __restrict__ W0, const float* __restrict__ W1,
                        const float* __restrict__ W2, _Float16* __restrict__ Wt0,
                        _Float16* __restrict__ Wtp1, _Float16* __restrict__ Wtp2,
                        const float* __restrict__ as1, const float* __restrict__ ad1,
                        const float* __restrict__ as2, const float* __restrict__ ad2,
                        float* __restrict__ va,
                        float* __restrict__ bn, int* __restrict__ tick){
  int t = blockIdx.x * blockDim.x + threadIdx.x;
  if (t < n8){
    const float4* p = (const float4*)(x + (size_t)t * 8);
    float4 v0 = p[0], v1 = p[1];
    half8 h = {(_Float16)v0.x, (_Float16)v0.y, (_Float16)v0.z, (_Float16)v0.w,
               (_Float16)v1.x, (_Float16)v1.y, (_Float16)v1.z, (_Float16)v1.w};
    *(half8*)(xh + (size_t)t * 8) = h;
  }
  if (t < E){
    int dst = ei[E + t];
    rank[t] = atomicAdd(&cnt8[((size_t)dst << 3) | (t & 7)], 1);
  }
  if (t < 256) bn[t] = 0.f;
  if (t < 4) tick[t] = 0;
  if (t < 65536){
    int c = t & 255, k = t >> 8;
    Wt0[(size_t)c * 256 + k] = (_Float16)W0[(size_t)k * 256 + c];
  } else if (t < 81920){
    // post-GEMM B for layer 1: Wtp1[c][r=h*64+k] = 0.25*W1[k][h*64+c], c<64
    int u = t - 65536; int c = u & 63, r = u >> 6;
    Wtp1[(size_t)c * 256 + r] = (_Float16)(0.25f * W1[(size_t)(r & 63) * 256 + (r >> 6) * 64 + c]);
  } else if (t < 98304){
    int u = t - 81920; int c = u & 63, r = u >> 6;
    Wtp2[(size_t)c * 256 + r] = (_Float16)(0.25f * W2[(size_t)(r & 63) * 256 + (r >> 6) * 64 + c]);
  } else if (t < 99328){
    // Va[layer][j][sd*4+h] = sum_k W[j][h*64+k] * a[h][k]
    int u = t - 98304;
    int layer = u >> 9;
    int sd = (u >> 8) & 1;
    int u2 = u & 255;
    int c = u2 >> 2, h = u2 & 3;
    const float* Wl = layer ? W2 : W1;
    const float* av = layer ? (sd ? ad2 : as2) : (sd ? ad1 : as1);
    float acc = 0.f;
    #pragma unroll 4
    for (int k = 0; k < 64; k++)
      acc += Wl[(size_t)c * 256 + h * 64 + k] * av[h * 64 + k];
    va[layer * 512 + c * 8 + sd * 4 + h] = acc;
  }
}

// ---------------- CSR scans (degree = sum of 8 shards + 1 for the self-loop) ----------------
__global__ __launch_bounds__(256) void k_bsumscan(const int* __restrict__ cnt8, int n, int chunk,
                                                  int* __restrict__ part, int* __restrict__ ptr,
                                                  int* __restrict__ tick){
  __shared__ int s[256];
  __shared__ int amLast;
  int b = blockIdx.x, t = threadIdx.x;
  int lo = b * chunk, hi = min(n, lo + chunk);
  int v = 0;
  for (int i = lo + t; i < hi; i += 256){
    const int4* p = (const int4*)(cnt8 + ((size_t)i << 3));
    int4 a = p[0], c = p[1];
    v += a.x + a.y + a.z + a.w + c.x + c.y + c.z + c.w + 1;
  }
  s[t] = v;
  __syncthreads();
  #pragma unroll
  for (int off = 128; off > 0; off >>= 1){
    if (t < off) s[t] += s[t + off];
    __syncthreads();
  }
  if (t == 0) part[b] = s[0];
  __threadfence();
  if (t == 0) amLast = (atomicAdd(tick, 1) == (int)gridDim.x - 1) ? 1 : 0;
  __syncthreads();
  if (amLast){
    int pv = atomicAdd(&part[t], 0);
    s[t] = pv;
    __syncthreads();
    #pragma unroll
    for (int off = 1; off < 256; off <<= 1){
      int u = (t >= off) ? s[t - off] : 0;
      __syncthreads();
      s[t] += u;
      __syncthreads();
    }
    part[t] = s[t] - pv;
    if (t == 255) ptr[n] = s[255];
  }
}

__global__ __launch_bounds__(256) void k_localscan(const int* __restrict__ cnt8, const int* __restrict__ part,
                                                   int n, int chunk, int* __restrict__ ptr,
                                                   int* __restrict__ shb,
                                                   int* __restrict__ csr_src){
  __shared__ int s[256];
  int b = blockIdx.x, t = threadIdx.x;
  int i = b * chunk + t;
  bool act = (t < chunk && i < n);
  int4 a = {0,0,0,0}, c4 = {0,0,0,0};
  int c = 0;
  if (act){
    const int4* p = (const int4*)(cnt8 + ((size_t)i << 3));
    a = p[0]; c4 = p[1];
    c = a.x + a.y + a.z + a.w + c4.x + c4.y + c4.z + c4.w;
  }
  int v = act ? c + 1 : 0;
  s[t] = v;
  __syncthreads();
  #pragma unroll
  for (int off = 1; off < 256; off <<= 1){
    int u = (t >= off) ? s[t - off] : 0;
    __syncthreads();
    s[t] += u;
    __syncthreads();
  }
  if (act){
    int ex = part[b] + s[t] - v;
    ptr[i] = ex;
    // per-shard base offsets: shb[i*8+s] = ex + prefix(shards < s)
    int run = ex;
    int4 o0, o1;
    o0.x = run; run += a.x;
    o0.y = run; run += a.y;
    o0.z = run; run += a.z;
    o0.w = run; run += a.w;
    o1.x = run; run += c4.x;
    o1.y = run; run += c4.y;
    o1.z = run; run += c4.z;
    o1.w = run; run += c4.w;
    ((int4*)(shb + ((size_t)i << 3)))[0] = o0;
    ((int4*)(shb + ((size_t)i << 3)))[1] = o1;
    csr_src[ex + c] = i;     // self-loop after the c edges
  }
}

// ---------------- k_fill: lean standalone CSR fill (no atomics, full occupancy).
// Same random-access count as before: one shb read + one csr write per edge. ----------------
__global__ __launch_bounds__(256) void k_fill(const int* __restrict__ ei, int E,
                                              const int* __restrict__ rank,
                                              const int* __restrict__ shb,
                                              int* __restrict__ csr_src){
  int e = blockIdx.x * 256 + threadIdx.x;
  if (e < E){
    int dst = ei[E + e];
    csr_src[shb[((size_t)dst << 3) | (e & 7)] + rank[e]] = ei[e];
  }
}

// ---------------- layer-0 MFMA GEMM: 128 rows x 256 cols (pure) ----------------
template<int LAYER>
__global__ __launch_bounds__(256, 2) void k_gemm(const _Float16* __restrict__ Xh,
    const _Float16* __restrict__ Wt, const float* __restrict__ a_s, const float* __restrict__ a_d,
    __half* __restrict__ hb, float* __restrict__ al, float* __restrict__ ar, int nrows){
  constexpr int K = 256;
  __shared__ _Float16 Alds[4][129][8];
  __shared__ _Float16 Blds[4][257][8];
  int tid = threadIdx.x;
  int m0 = blockIdx.x * 128;
  int w = tid >> 6, l = tid & 63;
  int lm = l & 15, lq = l >> 4;
  f32x4 acc[8][4] = {};

  for (int k0 = 0; k0 < K; k0 += 32){
    #pragma unroll
    for (int it = 0; it < 2; it++){
      int gr = m0 + it * 64 + l;
      if (gr < nrows)
        llds16(Xh + (size_t)gr * K + k0 + w * 8, &Alds[w][it * 64][0]);
    }
    #pragma unroll
    for (int it = 0; it < 4; it++){
      int col = it * 64 + l;
      llds16(Wt + (size_t)col * K + k0 + w * 8, &Blds[w][it * 64][0]);
    }
    __syncthreads();
    half8 af[8];
    #pragma unroll
    for (int mf = 0; mf < 8; mf++) af[mf] = *(const half8*)&Alds[lq][mf * 16 + lm][0];
    #pragma unroll
    for (int j = 0; j < 4; j++){
      half8 bf = *(const half8*)&Blds[lq][(w * 4 + j) * 16 + lm][0];
      #pragma unroll
      for (int mf = 0; mf < 8; mf++)
        acc[mf][j] = __builtin_amdgcn_mfma_f32_16x16x32_f16(af[mf], bf, acc[mf][j], 0, 0, 0);
    }
    __syncthreads();
  }

  float asv[4], adv[4];
  #pragma unroll
  for (int j = 0; j < 4; j++){
    asv[j] = a_s[w * 64 + j * 16 + lm];
    adv[j] = a_d[w * 64 + j * 16 + lm];
  }
  #pragma unroll
  for (int mf = 0; mf < 8; mf++){
    #pragma unroll
    for (int reg = 0; reg < 4; reg++){
      float sl = acc[mf][0][reg] * asv[0] + acc[mf][1][reg] * asv[1]
               + acc[mf][2][reg] * asv[2] + acc[mf][3][reg] * asv[3];
      float sr = acc[mf][0][reg] * adv[0] + acc[mf][1][reg] * adv[1]
               + acc[mf][2][reg] * adv[2] + acc[mf][3][reg] * adv[3];
      #pragma unroll
      for (int off = 1; off < 16; off <<= 1){
        sl += __shfl_xor(sl, off);
        sr += __shfl_xor(sr, off);
      }
      int row = m0 + mf * 16 + lq * 4 + reg;
      if (lm == 0 && row < nrows){
        al[(size_t)row * 4 + w] = sl;
        ar[(size_t)row * 4 + w] = sr;
      }
      if (row < nrows){
        ushort4 pk;
        pk.x = __half_as_ushort(__float2half(acc[mf][0][reg]));
        pk.y = __half_as_ushort(__float2half(acc[mf][1][reg]));
        pk.z = __half_as_ushort(__float2half(acc[mf][2][reg]));
        pk.w = __half_as_ushort(__float2half(acc[mf][3][reg]));
        *(ushort4*)(hb + (size_t)row * 256 + w * 64 + lm * 4) = pk;
      }
    }
  }
}

// ---------------- layer-0 per-node softmax + aggregate (wave per node) ----------------
#define AGG_STEP(QV, POFF) { \
    int je = j + (POFF) + eh; \
    float w = wbase[je * 4 + hd]; \
    int4 qq = QV; \
    int jn = je + 8; \
    if (jn < deg){ \
      int s = sbase[jn]; \
      QV = *(const int4*)((const char*)hb + (((unsigned)s << 9) + choff)); \
    } \
    const __half2* h2 = (const __half2*)&qq; \
    float2 f0 = __half22float2(h2[0]); \
    float2 f1 = __half22float2(h2[1]); \
    float2 f2 = __half22float2(h2[2]); \
    float2 f3 = __half22float2(h2[3]); \
    a0 = fmaf(f0.x, w, a0); a1 = fmaf(f0.y, w, a1); \
    a2 = fmaf(f1.x, w, a2); a3 = fmaf(f1.y, w, a3); \
    a4 = fmaf(f2.x, w, a4); a5 = fmaf(f2.y, w, a5); \
    a6 = fmaf(f3.x, w, a6); a7 = fmaf(f3.y, w, a7); \
  }

__global__ __launch_bounds__(256, 8) void k_node(const int* __restrict__ ptr,
    const int* __restrict__ csr, const __half* __restrict__ hb,
    const float* __restrict__ al, const float* __restrict__ ar,
    const float* __restrict__ bias, float* __restrict__ out, int N){
  __shared__ float4 wsm[4][64];
  __shared__ int    ssm[4][64];
  int n = (blockIdx.x * blockDim.x + threadIdx.x) >> 6;
  int lane = threadIdx.x & 63;
  int wv = threadIdx.x >> 6;
  if (n >= N) return;
  int beg = ptr[n], end = ptr[n + 1];
  int deg = end - beg;
  float4 arv = *(const float4*)(ar + (size_t)n * 4);

  if (deg <= 64){
    int idx = beg + lane;
    bool act = idx < end;
    int mye = act ? csr[idx] : 0;
    int eh = lane >> 5;
    int hd = (lane >> 3) & 3;
    int c8 = lane & 7;
    unsigned choff = (unsigned)(hd * 128 + c8 * 16);

    float e0 = -1e30f, e1 = -1e30f, e2 = -1e30f, e3 = -1e30f;
    if (act){
      float4 av = *(const float4*)((const char*)al + ((unsigned)mye << 4));
      e0 = lrelu(av.x + arv.x); e1 = lrelu(av.y + arv.y);
      e2 = lrelu(av.z + arv.z); e3 = lrelu(av.w + arv.w);
    }
    int s0 = __shfl(mye, 0 + eh), s1 = __shfl(mye, 2 + eh);
    int s2 = __shfl(mye, 4 + eh), s3 = __shfl(mye, 6 + eh);
    int4 q0 = *(const int4*)((const char*)hb + (((unsigned)s0 << 9) + choff));
    int4 q1 = *(const int4*)((const char*)hb + (((unsigned)s1 << 9) + choff));
    int4 q2 = *(const int4*)((const char*)hb + (((unsigned)s2 << 9) + choff));
    int4 q3 = *(const int4*)((const char*)hb + (((unsigned)s3 << 9) + choff));

    float m0 = e0, m1 = e1, m2 = e2, m3 = e3;
    #pragma unroll
    for (int off = 32; off > 0; off >>= 1){
      m0 = fmaxf(m0, __shfl_xor(m0, off));
      m1 = fmaxf(m1, __shfl_xor(m1, off));
      m2 = fmaxf(m2, __shfl_xor(m2, off));
      m3 = fmaxf(m3, __shfl_xor(m3, off));
    }
    float w0 = __expf(e0 - m0), w1 = __expf(e1 - m1);
    float w2 = __expf(e2 - m2), w3 = __expf(e3 - m3);
    float d0 = w0, d1 = w1, d2 = w2, d3 = w3;
    #pragma unroll
    for (int off = 32; off > 0; off >>= 1){
      d0 += __shfl_xor(d0, off);
      d1 += __shfl_xor(d1, off);
      d2 += __shfl_xor(d2, off);
      d3 += __shfl_xor(d3, off);
    }
    wsm[wv][lane] = make_float4(w0 / (d0 + EPS_SM), w1 / (d1 + EPS_SM),
                                w2 / (d2 + EPS_SM), w3 / (d3 + EPS_SM));
    ssm[wv][lane] = mye;
    __builtin_amdgcn_wave_barrier();

    const float* wbase = (const float*)&wsm[wv][0];
    const int*   sbase = &ssm[wv][0];
    float a0=0.f,a1=0.f,a2=0.f,a3=0.f,a4=0.f,a5=0.f,a6=0.f,a7=0.f;
    for (int j = 0; j < deg; j += 8){
      AGG_STEP(q0, 0)
      AGG_STEP(q1, 2)
      AGG_STEP(q2, 4)
      AGG_STEP(q3, 6)
    }
    #pragma unroll
    for (int off = 32; off >= 8; off >>= 1){
      a0 += __shfl_xor(a0, off); a1 += __shfl_xor(a1, off);
      a2 += __shfl_xor(a2, off); a3 += __shfl_xor(a3, off);
      a4 += __shfl_xor(a4, off); a5 += __shfl_xor(a5, off);
      a6 += __shfl_xor(a6, off); a7 += __shfl_xor(a7, off);
    }
    if (lane < 8){
      float* op = out + (size_t)n * 64 + c8 * 2;
      float2 b0 = *(const float2*)(bias + 0 * 16 + c8 * 2);
      float2 b1 = *(const float2*)(bias + 1 * 16 + c8 * 2);
      float2 b2 = *(const float2*)(bias + 2 * 16 + c8 * 2);
      float2 b3 = *(const float2*)(bias + 3 * 16 + c8 * 2);
      *(float2*)(op + 0)  = make_float2(a0 * 0.25f + b0.x, a4 * 0.25f + b0.y);
      *(float2*)(op + 16) = make_float2(a1 * 0.25f + b1.x, a5 * 0.25f + b1.y);
      *(float2*)(op + 32) = make_float2(a2 * 0.25f + b2.x, a6 * 0.25f + b2.y);
      *(float2*)(op + 48) = make_float2(a3 * 0.25f + b3.x, a7 * 0.25f + b3.y);
    }
  } else {
    int hd = lane >> 4;
    int t = lane & 15;
    const __half* hbase = hb + hd * 64 + t * 4;
    float ax = 0.f, ay = 0.f, az = 0.f, aw = 0.f;
    float m0 = -1e30f, m1 = -1e30f, m2 = -1e30f, m3 = -1e30f;
    for (int i = beg + lane; i < end; i += 64){
      int s = csr[i];
      float4 av = *(const float4*)(al + (size_t)s * 4);
      m0 = fmaxf(m0, lrelu(av.x + arv.x));
      m1 = fmaxf(m1, lrelu(av.y + arv.y));
      m2 = fmaxf(m2, lrelu(av.z + arv.z));
      m3 = fmaxf(m3, lrelu(av.w + arv.w));
    }
    #pragma unroll
    for (int off = 32; off > 0; off >>= 1){
      m0 = fmaxf(m0, __shfl_xor(m0, off));
      m1 = fmaxf(m1, __shfl_xor(m1, off));
      m2 = fmaxf(m2, __shfl_xor(m2, off));
      m3 = fmaxf(m3, __shfl_xor(m3, off));
    }
    float d0 = 0.f, d1 = 0.f, d2 = 0.f, d3 = 0.f;
    for (int i = beg + lane; i < end; i += 64){
      int s = csr[i];
      float4 av = *(const float4*)(al + (size_t)s * 4);
      d0 += __expf(lrelu(av.x + arv.x) - m0);
      d1 += __expf(lrelu(av.y + arv.y) - m1);
      d2 += __expf(lrelu(av.z + arv.z) - m2);
      d3 += __expf(lrelu(av.w + arv.w) - m3);
    }
    #pragma unroll
    for (int off = 32; off > 0; off >>= 1){
      d0 += __shfl_xor(d0, off);
      d1 += __shfl_xor(d1, off);
      d2 += __shfl_xor(d2, off);
      d3 += __shfl_xor(d3, off);
    }
    float i0 = 1.f / (d0 + EPS_SM), i1 = 1.f / (d1 + EPS_SM);
    float i2 = 1.f / (d2 + EPS_SM), i3 = 1.f / (d3 + EPS_SM);
    float arh = hd == 0 ? arv.x : hd == 1 ? arv.y : hd == 2 ? arv.z : arv.w;
    float mh  = hd == 0 ? m0 : hd == 1 ? m1 : hd == 2 ? m2 : m3;
    float ih  = hd == 0 ? i0 : hd == 1 ? i1 : hd == 2 ? i2 : i3;
    for (int i = beg; i < end; i++){
      int s = csr[i];
      float w = __expf(lrelu(al[(size_t)s * 4 + hd] + arh) - mh) * ih;
      ushort4 u = *(const ushort4*)(hbase + (size_t)s * 256);
      ax = fmaf(__half2float(__ushort_as_half(u.x)), w, ax);
      ay = fmaf(__half2float(__ushort_as_half(u.y)), w, ay);
      az = fmaf(__half2float(__ushort_as_half(u.z)), w, az);
      aw = fmaf(__half2float(__ushort_as_half(u.w)), w, aw);
    }
    #pragma unroll
    for (int off = 16; off <= 32; off <<= 1){
      ax += __shfl_xor(ax, off);
      ay += __shfl_xor(ay, off);
      az += __shfl_xor(az, off);
      aw += __shfl_xor(aw, off);
    }
    if (lane < 16){
      float* op = out + (size_t)n * 64;
      op[t]      = ax * 0.25f + bias[t];
      op[16 + t] = ay * 0.25f + bias[16 + t];
      op[32 + t] = az * 0.25f + bias[32 + t];
      op[48 + t] = aw * 0.25f + bias[48 + t];
    }
  }
}

// ---------------- k_attn: BN+ReLU -> y fp16, al/ar = y @ Va  (16 lanes/node) ----------------
__global__ __launch_bounds__(256) void k_attn(const float* __restrict__ bufA,
    const float* __restrict__ scale, const float* __restrict__ shift,
    const float* __restrict__ va,   // [64][8] : s0..s3,d0..d3
    _Float16* __restrict__ yh, float* __restrict__ al, float* __restrict__ ar, int N){
  int n = (blockIdx.x * 256 + threadIdx.x) >> 4;
  int t = threadIdx.x & 15;
  if (n >= N) return;
  float4 v  = *(const float4*)(bufA + (size_t)n * 64 + t * 4);
  float4 sc = *(const float4*)(scale + t * 4);
  float4 sh = *(const float4*)(shift + t * 4);
  float y0 = fmaxf(fmaf(v.x, sc.x, sh.x), 0.f);
  float y1 = fmaxf(fmaf(v.y, sc.y, sh.y), 0.f);
  float y2 = fmaxf(fmaf(v.z, sc.z, sh.z), 0.f);
  float y3 = fmaxf(fmaf(v.w, sc.w, sh.w), 0.f);
  ushort4 pk;
  pk.x = __half_as_ushort(__float2half(y0));
  pk.y = __half_as_ushort(__float2half(y1));
  pk.z = __half_as_ushort(__float2half(y2));
  pk.w = __half_as_ushort(__float2half(y3));
  *(ushort4*)(yh + (size_t)n * 64 + t * 4) = pk;

  float p0=0,p1=0,p2=0,p3=0,p4=0,p5=0,p6=0,p7=0;
  #define ATT_ACC(YV, J) { \
    const float4 a = *(const float4*)(va + (t * 4 + (J)) * 8); \
    const float4 b = *(const float4*)(va + (t * 4 + (J)) * 8 + 4); \
    p0 = fmaf(YV, a.x, p0); p1 = fmaf(YV, a.y, p1); \
    p2 = fmaf(YV, a.z, p2); p3 = fmaf(YV, a.w, p3); \
    p4 = fmaf(YV, b.x, p4); p5 = fmaf(YV, b.y, p5); \
    p6 = fmaf(YV, b.z, p6); p7 = fmaf(YV, b.w, p7); }
  ATT_ACC(y0, 0) ATT_ACC(y1, 1) ATT_ACC(y2, 2) ATT_ACC(y3, 3)
  #undef ATT_ACC
  #pragma unroll
  for (int off = 1; off < 16; off <<= 1){
    p0 += __shfl_xor(p0, off); p1 += __shfl_xor(p1, off);
    p2 += __shfl_xor(p2, off); p3 += __shfl_xor(p3, off);
    p4 += __shfl_xor(p4, off); p5 += __shfl_xor(p5, off);
    p6 += __shfl_xor(p6, off); p7 += __shfl_xor(p7, off);
  }
  if (t == 0){
    *(float4*)(al + (size_t)n * 4) = make_float4(p0, p1, p2, p3);
    *(float4*)(ar + (size_t)n * 4) = make_float4(p4, p5, p6, p7);
  }
}

// ---------------- k_agg: softmax + aggregate y (64ch) per head -> agg fp16 [N][h*64+c].
// TWO nodes per wave (32 lanes each) when both degs <= 32 (~99.8% of pairs). ----------------
#define AGG_FMA(Q, W4) { \
    union { uint2 u; __half2 h[2]; } _u; _u.u = (Q); \
    float2 _fa = __half22float2(_u.h[0]); \
    float2 _fb = __half22float2(_u.h[1]); \
    a0.x = fmaf(_fa.x, (W4).x, a0.x); a0.y = fmaf(_fa.y, (W4).x, a0.y); \
    a0.z = fmaf(_fb.x, (W4).x, a0.z); a0.w = fmaf(_fb.y, (W4).x, a0.w); \
    a1.x = fmaf(_fa.x, (W4).y, a1.x); a1.y = fmaf(_fa.y, (W4).y, a1.y); \
    a1.z = fmaf(_fb.x, (W4).y, a1.z); a1.w = fmaf(_fb.y, (W4).y, a1.w); \
    a2.x = fmaf(_fa.x, (W4).z, a2.x); a2.y = fmaf(_fa.y, (W4).z, a2.y); \
    a2.z = fmaf(_fb.x, (W4).z, a2.z); a2.w = fmaf(_fb.y, (W4).z, a2.w); \
    a3.x = fmaf(_fa.x, (W4).w, a3.x); a3.y = fmaf(_fa.y, (W4).w, a3.y); \
    a3.z = fmaf(_fb.x, (W4).w, a3.z); a3.w = fmaf(_fb.y, (W4).w, a3.w); \
  }

#define AGG_WRITE(n, t) { \
    char* base = (char*)aggh + ((size_t)(n) << 9) + (t) * 8; \
    ushort4 pk; \
    pk.x = __half_as_ushort(__float2half(a0.x)); \
    pk.y = __half_as_ushort(__float2half(a0.y)); \
    pk.z = __half_as_ushort(__float2half(a0.z)); \
    pk.w = __half_as_ushort(__float2half(a0.w)); \
    *(ushort4*)(base + 0)   = pk; \
    pk.x = __half_as_ushort(__float2half(a1.x)); \
    pk.y = __half_as_ushort(__float2half(a1.y)); \
    pk.z = __half_as_ushort(__float2half(a1.z)); \
    pk.w = __half_as_ushort(__float2half(a1.w)); \
    *(ushort4*)(base + 128) = pk; \
    pk.x = __half_as_ushort(__float2half(a2.x)); \
    pk.y = __half_as_ushort(__float2half(a2.y)); \
    pk.z = __half_as_ushort(__float2half(a2.z)); \
    pk.w = __half_as_ushort(__float2half(a2.w)); \
    *(ushort4*)(base + 256) = pk; \
    pk.x = __half_as_ushort(__float2half(a3.x)); \
    pk.y = __half_as_ushort(__float2half(a3.y)); \
    pk.z = __half_as_ushort(__float2half(a3.z)); \
    pk.w = __half_as_ushort(__float2half(a3.w)); \
    *(ushort4*)(base + 384) = pk; \
  }

__global__ __launch_bounds__(256, 8) void k_agg(const int* __restrict__ ptr,
    const int* __restrict__ csr, const _Float16* __restrict__ yh,
    const float* __restrict__ al, const float* __restrict__ ar,
    __half* __restrict__ aggh, int N){
  __shared__ float4 wsm[4][64];
  __shared__ int    ssm[4][64];
  int lane = threadIdx.x & 63;
  int wv = threadIdx.x >> 6;
  int base = (blockIdx.x * 4 + wv) * 2;
  if (base >= N) return;

  int begA = ptr[base];
  int endA = ptr[base + 1];
  int degA = endA - begA;
  bool dual = (base + 1 < N);
  int endB = dual ? ptr[base + 2] : endA;
  int degB = endB - endA;    // beg of node base+1 is endA (contiguous CSR)

  if (dual && degA <= 32 && degB <= 32){
    // ---------------- fast path: node half h2 = lane>>5 ----------------
    int h2 = lane >> 5;
    int l32 = lane & 31;
    int es = (lane >> 4) & 1;    // edge slot within half
    int t = lane & 15;           // channel quad
    int n = base + h2;
    int beg = h2 ? endA : begA;
    int deg = h2 ? degB : degA;
    float4 arv = *(const float4*)(ar + (size_t)n * 4);

    bool act = l32 < deg;
    int mye = act ? csr[beg + l32] : 0;
    float e0 = -1e30f, e1 = -1e30f, e2 = -1e30f, e3 = -1e30f;
    if (act){
      float4 av = *(const float4*)((const char*)al + ((unsigned)mye << 4));
      e0 = lrelu(av.x + arv.x); e1 = lrelu(av.y + arv.y);
      e2 = lrelu(av.z + arv.z); e3 = lrelu(av.w + arv.w);
    }
    // prefetch edges {es} and {2+es} of this node while the softmax reduces
    int sA = __shfl(mye, h2 * 32 + es);
    int sB = __shfl(mye, h2 * 32 + 2 + es);
    uint2 qA = *(const uint2*)((const char*)yh + (((unsigned)sA) << 7) + t * 8);
    uint2 qB = *(const uint2*)((const char*)yh + (((unsigned)sB) << 7) + t * 8);

    float m0 = e0, m1 = e1, m2 = e2, m3 = e3;
    #pragma unroll
    for (int off = 16; off > 0; off >>= 1){
      m0 = fmaxf(m0, __shfl_xor(m0, off));
      m1 = fmaxf(m1, __shfl_xor(m1, off));
      m2 = fmaxf(m2, __shfl_xor(m2, off));
      m3 = fmaxf(m3, __shfl_xor(m3, off));
    }
    float w0 = __expf(e0 - m0), w1 = __expf(e1 - m1);
    float w2 = __expf(e2 - m2), w3 = __expf(e3 - m3);
    float d0 = w0, d1 = w1, d2 = w2, d3 = w3;
    #pragma unroll
    for (int off = 16; off > 0; off >>= 1){
      d0 += __shfl_xor(d0, off);
      d1 += __shfl_xor(d1, off);
      d2 += __shfl_xor(d2, off);
      d3 += __shfl_xor(d3, off);
    }
    wsm[wv][lane] = make_float4(w0 / (d0 + EPS_SM), w1 / (d1 + EPS_SM),
                                w2 / (d2 + EPS_SM), w3 / (d3 + EPS_SM));
    ssm[wv][lane] = mye;
    __builtin_amdgcn_wave_barrier();

    float4 a0 = {0,0,0,0}, a1 = {0,0,0,0}, a2 = {0,0,0,0}, a3 = {0,0,0,0};
    int lbase = h2 * 32;
    for (int j = 0; j < deg; j += 4){
      uint2 cur = qA;
      if (j + 4 < deg){
        int s2 = ssm[wv][lbase + j + 4 + es];
        qA = *(const uint2*)((const char*)yh + (((unsigned)s2) << 7) + t * 8);
      }
      float4 w4 = wsm[wv][lbase + j + es];
      AGG_FMA(cur, w4)
      uint2 curB = qB;
      if (j + 6 < deg){
        int s3 = ssm[wv][lbase + j + 6 + es];
        qB = *(const uint2*)((const char*)yh + (((unsigned)s3) << 7) + t * 8);
      }
      float4 w4b = wsm[wv][lbase + j + 2 + es];
      AGG_FMA(curB, w4b)
    }
    // combine the 2 edge slots (xor 16 stays within the 32-lane half)
    #define R16(V) { V += __shfl_xor(V, 16); }
    R16(a0.x) R16(a0.y) R16(a0.z) R16(a0.w)
    R16(a1.x) R16(a1.y) R16(a1.z) R16(a1.w)
    R16(a2.x) R16(a2.y) R16(a2.z) R16(a2.w)
    R16(a3.x) R16(a3.y) R16(a3.z) R16(a3.w)
    #undef R16
    if (es == 0) AGG_WRITE(n, t)
    return;
  }

  // ---------------- sequential fallback: full wave per node ----------------
  int nEnd = dual ? base + 2 : base + 1;
  for (int n = base; n < nEnd; n++){
    int beg = ptr[n], end = ptr[n + 1];
    int deg = end - beg;
    float4 arv = *(const float4*)(ar + (size_t)n * 4);
    int eh = lane >> 4;
    int t  = lane & 15;
    float4 a0 = {0,0,0,0}, a1 = {0,0,0,0}, a2 = {0,0,0,0}, a3 = {0,0,0,0};

    if (deg <= 64){
      int idx = beg + lane;
      bool act = idx < end;
      int mye = act ? csr[idx] : 0;
      float e0 = -1e30f, e1 = -1e30f, e2 = -1e30f, e3 = -1e30f;
      if (act){
        float4 av = *(const float4*)((const char*)al + ((unsigned)mye << 4));
        e0 = lrelu(av.x + arv.x); e1 = lrelu(av.y + arv.y);
        e2 = lrelu(av.z + arv.z); e3 = lrelu(av.w + arv.w);
      }
      int sA = __shfl(mye, eh);
      int sB = __shfl(mye, 4 + eh);
      uint2 qA = *(const uint2*)((const char*)yh + (((unsigned)sA) << 7) + t * 8);
      uint2 qB = *(const uint2*)((const char*)yh + (((unsigned)sB) << 7) + t * 8);

      float m0 = e0, m1 = e1, m2 = e2, m3 = e3;
      #pragma unroll
      for (int off = 32; off > 0; off >>= 1){
        m0 = fmaxf(m0, __shfl_xor(m0, off));
        m1 = fmaxf(m1, __shfl_xor(m1, off));
        m2 = fmaxf(m2, __shfl_xor(m2, off));
        m3 = fmaxf(m3, __shfl_xor(m3, off));
      }
      float w0 = __expf(e0 - m0), w1 = __expf(e1 - m1);
      float w2 = __expf(e2 - m2), w3 = __expf(e3 - m3);
      float d0 = w0, d1 = w1, d2 = w2, d3 = w3;
      #pragma unroll
      for (int off = 32; off > 0; off >>= 1){
        d0 += __shfl_xor(d0, off);
        d1 += __shfl_xor(d1, off);
        d2 += __shfl_xor(d2, off);
        d3 += __shfl_xor(d3, off);
      }
      wsm[wv][lane] = make_float4(w0 / (d0 + EPS_SM), w1 / (d1 + EPS_SM),
                                  w2 / (d2 + EPS_SM), w3 / (d3 + EPS_SM));
      ssm[wv][lane] = mye;
      __builtin_amdgcn_wave_barrier();

      for (int j = 0; j < deg; j += 8){
        uint2 cur = qA;
        if (j + 8 < deg){
          int s2 = ssm[wv][j + 8 + eh];
          qA = *(const uint2*)((const char*)yh + (((unsigned)s2) << 7) + t * 8);
        }
        float4 w4 = wsm[wv][j + eh];
        AGG_FMA(cur, w4)
        uint2 curB = qB;
        if (j + 12 < deg){
          int s3 = ssm[wv][j + 12 + eh];
          qB = *(const uint2*)((const char*)yh + (((unsigned)s3) << 7) + t * 8);
        }
        float4 w4b = wsm[wv][j + 4 + eh];
        AGG_FMA(curB, w4b)
      }
      __builtin_amdgcn_wave_barrier();
    } else {
      // rare: deg > 64
      float m0 = -1e30f, m1 = -1e30f, m2 = -1e30f, m3 = -1e30f;
      for (int i = beg + lane; i < end; i += 64){
        int s = csr[i];
        float4 av = *(const float4*)(al + (size_t)s * 4);
        m0 = fmaxf(m0, lrelu(av.x + arv.x));
        m1 = fmaxf(m1, lrelu(av.y + arv.y));
        m2 = fmaxf(m2, lrelu(av.z + arv.z));
        m3 = fmaxf(m3, lrelu(av.w + arv.w));
      }
      #pragma unroll
      for (int off = 32; off > 0; off >>= 1){
        m0 = fmaxf(m0, __shfl_xor(m0, off));
        m1 = fmaxf(m1, __shfl_xor(m1, off));
        m2 = fmaxf(m2, __shfl_xor(m2, off));
        m3 = fmaxf(m3, __shfl_xor(m3, off));
      }
      float d0 = 0.f, d1 = 0.f, d2 = 0.f, d3 = 0.f;
      for (int i = beg + lane; i < end; i += 64){
        int s = csr[i];
        float4 av = *(const float4*)(al + (size_t)s * 4);
        d0 += __expf(lrelu(av.x + arv.x) - m0);
        d1 += __expf(lrelu(av.y + arv.y) - m1);
        d2 += __expf(lrelu(av.z + arv.z) - m2);
        d3 += __expf(lrelu(av.w + arv.w) - m3);
      }
      #pragma unroll
      for (int off = 32; off > 0; off >>= 1){
        d0 += __shfl_xor(d0, off);
        d1 += __shfl_xor(d1, off);
        d2 += __shfl_xor(d2, off);
        d3 += __shfl_xor(d3, off);
      }
      float i0 = 1.f / (d0 + EPS_SM), i1 = 1.f / (d1 + EPS_SM);
      float i2 = 1.f / (d2 + EPS_SM), i3 = 1.f / (d3 + EPS_SM);
      for (int i = beg; i < end; i += 4){
        int ie = i + eh;
        float w0 = 0.f, w1 = 0.f, w2 = 0.f, w3 = 0.f;
        int s = 0;
        if (ie < end){
          s = csr[ie];
          float4 av = *(const float4*)(al + (size_t)s * 4);
          w0 = __expf(lrelu(av.x + arv.x) - m0) * i0;
          w1 = __expf(lrelu(av.y + arv.y) - m1) * i1;
          w2 = __expf(lrelu(av.z + arv.z) - m2) * i2;
          w3 = __expf(lrelu(av.w + arv.w) - m3) * i3;
        }
        uint2 q = *(const uint2*)((const char*)yh + (((unsigned)s) << 7) + t * 8);
        float4 w4 = make_float4(w0, w1, w2, w3);
        AGG_FMA(q, w4)
      }
    }

    // combine the 4 edge-slot groups (lanes t, t+16, t+32, t+48)
    #define RED2(V) { V += __shfl_xor(V, 16); V += __shfl_xor(V, 32); }
    RED2(a0.x) RED2(a0.y) RED2(a0.z) RED2(a0.w)
    RED2(a1.x) RED2(a1.y) RED2(a1.z) RED2(a1.w)
    RED2(a2.x) RED2(a2.y) RED2(a2.z) RED2(a2.w)
    RED2(a3.x) RED2(a3.y) RED2(a3.z) RED2(a3.w)
    #undef RED2
    if (eh == 0) AGG_WRITE(n, t)
    __builtin_amdgcn_wave_barrier();
  }
}

// ---------------- k_gemmp: out[N,64] = agg[N,256] @ Bt^T + bias (MFMA, 256 rows/block) ----------------
__global__ __launch_bounds__(256, 2) void k_gemmp(const _Float16* __restrict__ A,
    const _Float16* __restrict__ Bt,   // [64 cols][256 K]
    const float* __restrict__ bias, float* __restrict__ out, int nrows){
  __shared__ _Float16 Alds[4][257][8];
  __shared__ _Float16 Blds[4][65][8];
  int tid = threadIdx.x;
  int m0 = blockIdx.x * 256;
  int w = tid >> 6, l = tid & 63;
  int lm = l & 15, lq = l >> 4;
  f32x4 acc[4][4] = {};
  for (int k0 = 0; k0 < 256; k0 += 32){
    #pragma unroll
    for (int it = 0; it < 4; it++){
      int gr = m0 + it * 64 + l;
      if (gr < nrows)
        llds16(A + (size_t)gr * 256 + k0 + w * 8, &Alds[w][it * 64][0]);
    }
    llds16(Bt + (size_t)l * 256 + k0 + w * 8, &Blds[w][0][0]);
    __syncthreads();
    half8 af[4];
    #pragma unroll
    for (int mf = 0; mf < 4; mf++) af[mf] = *(const half8*)&Alds[lq][w * 64 + mf * 16 + lm][0];
    #pragma unroll
    for (int j = 0; j < 4; j++){
      half8 bf = *(const half8*)&Blds[lq][j * 16 + lm][0];
      #pragma unroll
      for (int mf = 0; mf < 4; mf++)
        acc[mf][j] = __builtin_amdgcn_mfma_f32_16x16x32_f16(af[mf], bf, acc[mf][j], 0, 0, 0);
    }
    __syncthreads();
  }
  float bv[4];
  #pragma unroll
  for (int j = 0; j < 4; j++) bv[j] = bias[j * 16 + lm];
  #pragma unroll
  for (int mf = 0; mf < 4; mf++){
    #pragma unroll
    for (int reg = 0; reg < 4; reg++){
      int row = m0 + w * 64 + mf * 16 + lq * 4 + reg;
      if (row < nrows){
        #pragma unroll
        for (int j = 0; j < 4; j++)
          out[(size_t)row * 64 + j * 16 + lm] = acc[mf][j][reg] + bv[j];
      }
    }
  }
}

// ---------------- BatchNorm stats + fused finalize -> scale/shift ----------------
__global__ __launch_bounds__(256) void k_bnstats(const float* __restrict__ x, int N,
                                                 float* __restrict__ gsum, float* __restrict__ gsq,
                                                 int* __restrict__ tick,
                                                 const float* __restrict__ g, const float* __restrict__ be,
                                                 float* __restrict__ scale, float* __restrict__ shift){
  int c = threadIdx.x & 63;
  int rg = threadIdx.x >> 6;
  float s = 0.f, q = 0.f;
  for (int r = blockIdx.x * 4 + rg; r < N; r += gridDim.x * 4){
    float v = x[(size_t)r * 64 + c];
    s += v; q += v * v;
  }
  __shared__ float ls[4][64], lq[4][64];
  __shared__ int amLast;
  ls[rg][c] = s; lq[rg][c] = q;
  __syncthreads();
  if (rg == 0){
    s = ls[0][c] + ls[1][c] + ls[2][c] + ls[3][c];
    q = lq[0][c] + lq[1][c] + lq[2][c] + lq[3][c];
    atomicAdd(&gsum[c], s);
    atomicAdd(&gsq[c], q);
  }
  __threadfence();
  if (threadIdx.x == 0)
    amLast = (atomicAdd(tick, 1) == (int)gridDim.x - 1) ? 1 : 0;
  __syncthreads();
  if (amLast && threadIdx.x < 64){
    float gs = atomicAdd(&gsum[c], 0.f);
    float gq = atomicAdd(&gsq[c], 0.f);
    float m = gs / (float)N;
    float v = gq / (float)N - m * m;
    float sc = g[c] * rsqrtf(v + EPS_BN);
    scale[c] = sc;
    shift[c] = be[c] - m * sc;
  }
}

// ---------------- launcher ----------------
extern "C" void kernel_launch(void* const* d_in, const int* in_sizes, int n_in,
                              void* d_out, int out_size, void* d_ws, size_t ws_size,
                              hipStream_t stream){
  const float* x  = (const float*)d_in[0];
  const int*   ei = (const int*)d_in[1];
  const float* W[3]  = {(const float*)d_in[2], (const float*)d_in[6],  (const float*)d_in[10]};
  const float* AS[3] = {(const float*)d_in[3], (const float*)d_in[7],  (const float*)d_in[11]};
  const float* AD[3] = {(const float*)d_in[4], (const float*)d_in[8],  (const float*)d_in[12]};
  const float* BI[3] = {(const float*)d_in[5], (const float*)d_in[9],  (const float*)d_in[13]};
  const float* G[2]  = {(const float*)d_in[14], (const float*)d_in[16]};
  const float* BE[2] = {(const float*)d_in[15], (const float*)d_in[17]};
  const int N = in_sizes[0] / 256;
  const int E = in_sizes[1] / 2;
  const int EN = E + N;

  char* wsb = (char*)d_ws;
  size_t off = 0;
  auto alloc = [&](size_t bytes) -> char* {
    char* p = wsb + off;
    off = (off + bytes + 255) & ~(size_t)255;
    return p;
  };
  int* cnt8     = (int*)alloc((size_t)N * 8 * 4);
  int* rowptr   = (int*)alloc((size_t)(N + 1) * 4);
  int* part     = (int*)alloc(256 * 4);
  int* shb      = (int*)alloc((size_t)N * 8 * 4);
  int* rank     = (int*)alloc((size_t)E * 4);
  int* csr      = (int*)alloc((size_t)EN * 4);
  _Float16* xh  = (_Float16*)alloc((size_t)N * 256 * 2);
  _Float16* Wt0 = (_Float16*)alloc((size_t)256 * 256 * 2);
  _Float16* Wtp1= (_Float16*)alloc((size_t)64 * 256 * 2);
  _Float16* Wtp2= (_Float16*)alloc((size_t)64 * 256 * 2);
  __half* hb    = (__half*)alloc((size_t)N * 256 * 2);   // layer0 h; reused as agg for layers 1/2
  float* al     = (float*)alloc((size_t)N * 4 * 4);
  float* ar     = (float*)alloc((size_t)N * 4 * 4);
  float* bufA   = (float*)alloc((size_t)N * 64 * 4);
  _Float16* yh  = (_Float16*)alloc((size_t)N * 64 * 2);
  float* va     = (float*)alloc(1024 * 4);               // 2 layers x [64][8]
  float* bn     = (float*)alloc(256 * 4);
  int*   tick   = (int*)alloc(4 * 4);
  float* murs   = (float*)alloc(128 * 4);   // scale[64], shift[64]

  const int chunk = (N + 255) / 256;
  const int n8 = N * 32;
  const int nodeGrid = (N + 3) / 4;
  const int aggGrid = (N + 7) / 8;          // 2 nodes per wave
  const int attnGrid = (N + 15) / 16;
  const int gemmpGrid = (N + 255) / 256;

  hipMemsetAsync(cnt8, 0, (size_t)N * 8 * 4, stream);
  k_prep1<<<(n8 + 255) / 256, 256, 0, stream>>>(x, xh, n8, ei, E, cnt8, rank,
                                                W[0], W[1], W[2], Wt0, Wtp1, Wtp2,
                                                AS[1], AD[1], AS[2], AD[2], va, bn, tick);
  k_bsumscan<<<256, 256, 0, stream>>>(cnt8, N, chunk, part, rowptr, tick + 2);
  k_localscan<<<256, 256, 0, stream>>>(cnt8, part, N, chunk, rowptr, shb, csr);

  int gemmGrid = (N + 127) / 128;
  // layer 0: pure GEMM; CSR fill as lean standalone kernel (full occupancy)
  k_gemm<0><<<gemmGrid, 256, 0, stream>>>(xh, Wt0, AS[0], AD[0], hb, al, ar, N);
  k_fill<<<(E + 255) / 256, 256, 0, stream>>>(ei, E, rank, shb, csr);
  k_node<<<nodeGrid, 256, 0, stream>>>(rowptr, csr, hb, al, ar, BI[0], bufA, N);
  k_bnstats<<<256, 256, 0, stream>>>(bufA, N, bn, bn + 64, tick, G[0], BE[0], murs, murs + 64);
  // layer 1: aggregate-then-GEMM (payload = 64-ch y)
  k_attn<<<attnGrid, 256, 0, stream>>>(bufA, murs, murs + 64, va, yh, al, ar, N);
  k_agg<<<aggGrid, 256, 0, stream>>>(rowptr, csr, yh, al, ar, hb, N);
  k_gemmp<<<gemmpGrid, 256, 0, stream>>>((const _Float16*)hb, Wtp1, BI[1], bufA, N);
  k_bnstats<<<256, 256, 0, stream>>>(bufA, N, bn + 128, bn + 192, tick + 1, G[1], BE[1], murs, murs + 64);
  // layer 2
  k_attn<<<attnGrid, 256, 0, stream>>>(bufA, murs, murs + 64, va + 512, yh, al, ar, N);
  k_agg<<<aggGrid, 256, 0, stream>>>(rowptr, csr, yh, al, ar, hb, N);
  k_gemmp<<<gemmpGrid, 256, 0, stream>>>((const _Float16*)hb, Wtp2, BI[2], (float*)d_out, N);
}